// Round 8
// baseline (504.271 us; speedup 1.0000x reference)
//
#include <hip/hip_runtime.h>
#include <hip/hip_bf16.h>
#include <stdint.h>
#include <stddef.h>

typedef __hip_bfloat16 bf16;
typedef __attribute__((ext_vector_type(8))) short bhalf8;
typedef __attribute__((ext_vector_type(4))) short short4v;
typedef __attribute__((ext_vector_type(4))) float floatx4;

static __device__ __forceinline__ float b2f(bf16 v) { return __bfloat162float(v); }
static __device__ __forceinline__ bf16  f2b(float v) { return __float2bfloat16(v); }
static __device__ __forceinline__ short f2s(float v) {
    union { bf16 b; short s; } u; u.b = __float2bfloat16(v); return u.s;
}

// dtype-agnostic scalar load: flag==1 -> fp32 data, flag==0 -> bf16 data
static __device__ __forceinline__ float loadf(const void* p, size_t i, int f32) {
    return f32 ? ((const float*)p)[i] : b2f(((const bf16*)p)[i]);
}

// async global->LDS, 16B per lane. LDS dest must be wave-uniform base + lane*16.
static __device__ __forceinline__ void gl_lds16(const void* g, void* l) {
    __builtin_amdgcn_global_load_lds(
        (const __attribute__((address_space(1))) void*)g,
        (__attribute__((address_space(3))) void*)l, 16, 0, 0);
}

// load 4 consecutive mask values at 4-aligned index
static __device__ __forceinline__ void load_mask4(const void* mask, size_t idx,
                                                  int f32, float* mv) {
    if (f32) {
        float4 v = *(const float4*)((const float*)mask + idx);
        mv[0] = v.x; mv[1] = v.y; mv[2] = v.z; mv[3] = v.w;
    } else {
        const bf16* p = (const bf16*)mask + idx;
        #pragma unroll
        for (int t = 0; t < 4; t++) mv[t] = b2f(p[t]);
    }
}

// -------------------------------------------------------------------------
__global__ void detect_k(const void* w1raw, int* flag)
{
    if (threadIdx.x == 0 && blockIdx.x == 0) {
        const unsigned short* s = (const unsigned short*)w1raw;
        int bad = 0;
        for (int i = 0; i < 256; i++) {
            int e = (s[i] >> 7) & 0xFF;
            if (e > 0x85 || (e != 0 && e < 0x60)) bad++;
        }
        *flag = (bad > 16) ? 1 : 0;
    }
}

__global__ __launch_bounds__(256) void cvt_k(const void* __restrict__ src,
                                             bf16* __restrict__ dst, int n,
                                             const int* __restrict__ flag)
{
    const int f = *flag;
    int i = blockIdx.x * 256 + threadIdx.x;
    if (i < n) dst[i] = f ? f2b(((const float*)src)[i]) : ((const bf16*)src)[i];
}

// -------------------------------------------------------------------------
__global__ __launch_bounds__(256) void transpose_k(const void* __restrict__ in,
                                                   bf16* __restrict__ out,
                                                   int R, int C,
                                                   const int* __restrict__ flag)
{
    __shared__ bf16 tile[32][33];
    const int f = *flag;
    const int tx = threadIdx.x & 31;
    const int ty = threadIdx.x >> 5;
    const int c0 = blockIdx.x * 32;
    const int r0 = blockIdx.y * 32;
    #pragma unroll
    for (int yy = ty; yy < 32; yy += 8)
        tile[yy][tx] = f2b(loadf(in, (size_t)(r0 + yy) * C + c0 + tx, f));
    __syncthreads();
    #pragma unroll
    for (int yy = ty; yy < 32; yy += 8)
        out[(size_t)(c0 + yy) * R + r0 + tx] = tile[tx][yy];
}

// batched bf16 transpose: per b, in (1024 x 2048) -> out (2048 x 1024)
__global__ __launch_bounds__(256) void transpose_p(const bf16* __restrict__ in,
                                                   bf16* __restrict__ out)
{
    __shared__ bf16 tile[32][33];
    const int bz = blockIdx.z;
    const int tx = threadIdx.x & 31;
    const int ty = threadIdx.x >> 5;
    const int c0 = blockIdx.x * 32;
    const int r0 = blockIdx.y * 32;
    const bf16* ib = in + (size_t)bz * 1024 * 2048;
    bf16* ob = out + (size_t)bz * 1024 * 2048;
    #pragma unroll
    for (int yy = ty; yy < 32; yy += 8)
        tile[yy][tx] = ib[(size_t)(r0 + yy) * 2048 + c0 + tx];
    __syncthreads();
    #pragma unroll
    for (int yy = ty; yy < 32; yy += 8)
        ob[(size_t)(c0 + yy) * 1024 + r0 + tx] = tile[tx][yy];
}

// -------------------------------------------------------------------------
// Paired GEMM (layer 1): C = A@B[z]. m97 structure.
__global__ __launch_bounds__(256) void gemm_bt2(const bf16* __restrict__ A,
                                                const bf16* __restrict__ Bt0,
                                                const bf16* __restrict__ Bt1,
                                                bf16* __restrict__ C0,
                                                bf16* __restrict__ C1,
                                                int M, int N, int K)
{
    __shared__ __align__(16) short sA[128][32];
    __shared__ __align__(16) short sB[128][32];
    const int tid  = threadIdx.x;
    const int bx   = blockIdx.x, by = blockIdx.y;
    const bf16* Bt = blockIdx.z ? Bt1 : Bt0;
    bf16* C        = blockIdx.z ? C1  : C0;
    const int wave = tid >> 6, lane = tid & 63;
    const int wm   = wave >> 1, wn = wave & 1;
    const int lrow = lane & 15, quad = lane >> 4;

    floatx4 acc[4][4];
    #pragma unroll
    for (int i = 0; i < 4; i++)
        #pragma unroll
        for (int j = 0; j < 4; j++)
            acc[i][j] = (floatx4){0.f, 0.f, 0.f, 0.f};

    const int srow = wave * 32 + (lane >> 2);
    const int scol = (lane & 3) * 8;
    const bf16* gA0 = A  + (size_t)(by * 128 + srow) * K + scol;
    const bf16* gA1 = gA0 + (size_t)16 * K;
    const bf16* gB0 = Bt + (size_t)(bx * 128 + srow) * K + scol;
    const bf16* gB1 = gB0 + (size_t)16 * K;
    char* lA0 = (char*)&sA[0][0] + wave * 2048 + lane * 16;
    char* lA1 = lA0 + 1024;
    char* lB0 = (char*)&sB[0][0] + wave * 2048 + lane * 16;
    char* lB1 = lB0 + 1024;

    for (int k0 = 0; k0 < K; k0 += 32) {
        __syncthreads();
        gl_lds16(gA0 + k0, lA0);
        gl_lds16(gA1 + k0, lA1);
        gl_lds16(gB0 + k0, lB0);
        gl_lds16(gB1 + k0, lB1);
        __syncthreads();
        bhalf8 af[4], bfr[4];
        #pragma unroll
        for (int t = 0; t < 4; t++) af[t]  = *(const bhalf8*)&sA[wm * 64 + t * 16 + lrow][quad * 8];
        #pragma unroll
        for (int t = 0; t < 4; t++) bfr[t] = *(const bhalf8*)&sB[wn * 64 + t * 16 + lrow][quad * 8];
        #pragma unroll
        for (int tm = 0; tm < 4; tm++)
            #pragma unroll
            for (int tn = 0; tn < 4; tn++)
                acc[tm][tn] = __builtin_amdgcn_mfma_f32_16x16x32_bf16(af[tm], bfr[tn], acc[tm][tn], 0, 0, 0);
    }

    #pragma unroll
    for (int tm = 0; tm < 4; tm++) {
        #pragma unroll
        for (int tn = 0; tn < 4; tn++) {
            const int col = bx * 128 + wn * 64 + tn * 16 + lrow;
            #pragma unroll
            for (int r = 0; r < 4; r++) {
                const int row = by * 128 + wm * 64 + tm * 16 + quad * 4 + r;
                C[(size_t)row * N + col] = f2b(acc[tm][tn][r]);
            }
        }
    }
}

// -------------------------------------------------------------------------
// s_src/s_tgt for layer 1: wave-autonomous dot over f=256.
__global__ __launch_bounds__(256) void compute_sw(const bf16* __restrict__ p,
                                                  const void* __restrict__ a_src,
                                                  const void* __restrict__ a_tgt,
                                                  float* __restrict__ s_src_t,
                                                  float* __restrict__ s_tgt_t,
                                                  const int* __restrict__ flag)
{
    const int f32 = *flag;
    const int bh = blockIdx.x, b = bh >> 3, h = bh & 7;
    const int wave = threadIdx.x >> 6, lane = threadIdx.x & 63;
    const int n = blockIdx.y * 4 + wave;
    const bf16* pr = p + ((size_t)(b * 1024 + n)) * 2048 + h * 256;
    float ss = 0.f, st = 0.f;
    #pragma unroll
    for (int q = 0; q < 4; q++) {
        const int f = q * 64 + lane;
        float pv = b2f(pr[f]);
        ss = fmaf(pv, loadf(a_src, h * 256 + f, f32), ss);
        st = fmaf(pv, loadf(a_tgt, h * 256 + f, f32), st);
    }
    #pragma unroll
    for (int off = 32; off; off >>= 1) {
        ss += __shfl_down(ss, off, 64);
        st += __shfl_down(st, off, 64);
    }
    if (lane == 0) {
        s_src_t[bh * 1024 + n] = ss;
        s_tgt_t[bh * 1024 + n] = st;
    }
}

// -------------------------------------------------------------------------
// Fused layer-1 attention v2: 32-row x 256-col (full f) tile, BK=32, dbuf.
// Grid (32 by, 32 bh) = 1024 blocks (4/CU). No bx exp redundancy.
// Wave layout 1x4 over cols; each wave: 2 m-tiles x 4 n-tiles.
__global__ __launch_bounds__(256) void attn_fused(const float* __restrict__ s_src_t,
                                                  const float* __restrict__ s_tgt_t,
                                                  const void* __restrict__ mask,
                                                  const bf16* __restrict__ pT,
                                                  const bf16* __restrict__ sk,
                                                  const void* __restrict__ bias,
                                                  bf16* __restrict__ x2,
                                                  const int* __restrict__ flag)
{
    __shared__ __align__(16) short sA[2][32][32];    // exp numerators
    __shared__ __align__(16) short sB[2][256][32];   // pT tile (f x k)
    __shared__ float sInvl[32];

    const int tid = threadIdx.x;
    const int by = blockIdx.x, bh = blockIdx.y;
    const int b = bh >> 3, h = bh & 7;
    const int f32 = *flag;
    const int wave = tid >> 6, lane = tid & 63;
    const int lrow = lane & 15, quad = lane >> 4;

    // exp-gen assignment: 8 threads per row, 4 cols each
    const int row  = tid >> 3;            // 0..31
    const int col0 = (tid & 7) * 4;       // 0..28
    const float ssr = s_src_t[bh * 1024 + by * 32 + row];
    const size_t mrow0 = ((size_t)(b * 1024 + by * 32 + row)) << 10;
    const float* stbase = s_tgt_t + bh * 1024;

    // B staging: thread covers f-row tid>>2 (+64c), k-cols (tid&3)*8..+7
    const bf16* gB = pT + ((size_t)bh << 18) + (size_t)(tid >> 2) * 1024 + (tid & 3) * 8;

    floatx4 acc[2][4];
    #pragma unroll
    for (int i = 0; i < 2; i++)
        #pragma unroll
        for (int j = 0; j < 4; j++)
            acc[i][j] = (floatx4){0.f, 0.f, 0.f, 0.f};

    float lacc = 0.f;

    auto stageB = [&](int k0, int buf) {
        const bf16* g = gB + k0;
        char* l = (char*)&sB[buf][0][0] + tid * 16;
        #pragma unroll
        for (int c = 0; c < 4; c++)
            gl_lds16(g + (size_t)(64 * c) * 1024, l + c * 4096);
    };
    auto genA = [&](int k0, int buf) {
        float mv[4];
        load_mask4(mask, mrow0 + k0 + col0, f32, mv);
        float4 s4 = *(const float4*)(stbase + k0 + col0);
        float sv[4] = {s4.x, s4.y, s4.z, s4.w};
        short4v ev;
        #pragma unroll
        for (int t = 0; t < 4; t++) {
            float x = ssr + sv[t];
            x = fmaxf(x, 0.2f * x);          // leaky_relu(0.2)
            float e = __expf(x + mv[t]);
            lacc += e;
            ev[t] = f2s(e);
        }
        *(short4v*)&sA[buf][row][col0] = ev;
    };

    // prologue
    stageB(0, 0);
    genA(0, 0);

    int cur = 0;
    for (int k0 = 0; k0 < 1024; k0 += 32, cur ^= 1) {
        __syncthreads();                 // tile[cur] ready (vmcnt+lgkm drained)
        if (k0 + 32 < 1024) {
            stageB(k0 + 32, cur ^ 1);
            genA(k0 + 32, cur ^ 1);
        }
        bhalf8 af[2], bfr[4];
        #pragma unroll
        for (int mt = 0; mt < 2; mt++)
            af[mt] = *(const bhalf8*)&sA[cur][mt * 16 + lrow][quad * 8];
        #pragma unroll
        for (int nt = 0; nt < 4; nt++)
            bfr[nt] = *(const bhalf8*)&sB[cur][wave * 64 + nt * 16 + lrow][quad * 8];
        #pragma unroll
        for (int mt = 0; mt < 2; mt++)
            #pragma unroll
            for (int nt = 0; nt < 4; nt++)
                acc[mt][nt] = __builtin_amdgcn_mfma_f32_16x16x32_bf16(af[mt], bfr[nt], acc[mt][nt], 0, 0, 0);
    }

    // row denominators: 8 consecutive lanes share a row
    lacc += __shfl_xor(lacc, 1, 64);
    lacc += __shfl_xor(lacc, 2, 64);
    lacc += __shfl_xor(lacc, 4, 64);
    if ((tid & 7) == 0) sInvl[row] = 1.0f / lacc;
    __syncthreads();

    #pragma unroll
    for (int mt = 0; mt < 2; mt++) {
        #pragma unroll
        for (int r = 0; r < 4; r++) {
            const int rl = mt * 16 + quad * 4 + r;          // 0..31
            const int rg = by * 32 + rl;
            const float il = sInvl[rl];
            #pragma unroll
            for (int nt = 0; nt < 4; nt++) {
                const int col = wave * 64 + nt * 16 + lrow; // 0..255
                const int hf = h * 256 + col;
                const size_t idx = ((size_t)(b * 1024 + rg)) * 2048 + hf;
                float v = acc[mt][nt][r] * il + b2f(sk[idx]) + loadf(bias, hf, f32);
                v = (v > 0.f) ? v : expm1f(v);     // ELU
                x2[idx] = f2b(v);
            }
        }
    }
}

// -------------------------------------------------------------------------
// Wa[hh][k] = sum_f W2[k, h*256+f] * a[h][f], hh 0..7 = a_src2, 8..15 = a_tgt2.
__global__ __launch_bounds__(256) void wproj_k(const void* __restrict__ W2,
                                               const void* __restrict__ a_src2,
                                               const void* __restrict__ a_tgt2,
                                               float* __restrict__ Wa,
                                               const int* __restrict__ flag)
{
    __shared__ float sa[256];
    const int f32 = *flag;
    const int id = blockIdx.x * 256 + threadIdx.x;   // 0..32767
    const int hh = id >> 11, k = id & 2047, h = hh & 7;
    const void* a = (hh < 8) ? a_src2 : a_tgt2;
    sa[threadIdx.x] = loadf(a, h * 256 + threadIdx.x, f32);
    __syncthreads();
    float acc = 0.f;
    #pragma unroll 4
    for (int f = 0; f < 256; f++)
        acc = fmaf(loadf(W2, (size_t)k * 2048 + h * 256 + f, f32), sa[f], acc);
    Wa[hh * 2048 + k] = acc;
}

// -------------------------------------------------------------------------
// Layer-2 scores: ss/st[bh][n] = sum_k x2[b,n,k] * Wa[hh][k]. Block per node.
__global__ __launch_bounds__(256) void score2_k(const bf16* __restrict__ x2,
                                                const float* __restrict__ Wa,
                                                float* __restrict__ s_src_t,
                                                float* __restrict__ s_tgt_t)
{
    const int bid = blockIdx.x;           // b*1024 + n
    const int b = bid >> 10, n = bid & 1023;
    const int wave = threadIdx.x >> 6, lane = threadIdx.x & 63;
    const bf16* xr = x2 + (size_t)bid * 2048;
    float xv[32];
    #pragma unroll
    for (int q = 0; q < 32; q++) xv[q] = b2f(xr[q * 64 + lane]);
    #pragma unroll
    for (int c = 0; c < 4; c++) {
        const int hh = c * 4 + wave;      // 0..15
        const float* wr = Wa + hh * 2048;
        float acc = 0.f;
        #pragma unroll
        for (int q = 0; q < 32; q++) acc = fmaf(xv[q], wr[q * 64 + lane], acc);
        #pragma unroll
        for (int off = 32; off; off >>= 1) acc += __shfl_down(acc, off, 64);
        if (lane == 0) {
            if (hh < 8) s_src_t[(b * 8 + hh) * 1024 + n] = acc;
            else        s_tgt_t[(b * 8 + hh - 8) * 1024 + n] = acc;
        }
    }
}

// -------------------------------------------------------------------------
// Fused layer-2 denominators + weighted column sums (one kernel, two passes).
// Grid (32 bh, 32 ic of 32 rows). c[bh][j] += sum_i e[i,j]/l_i.
__global__ __launch_bounds__(256) void colsoft_k(const float* __restrict__ s_src_t,
                                                 const float* __restrict__ s_tgt_t,
                                                 const void* __restrict__ mask,
                                                 float* __restrict__ c,
                                                 const int* __restrict__ flag)
{
    __shared__ float sS[32];
    __shared__ float sIl[32];
    const int f32 = *flag;
    const int bh = blockIdx.x, ic = blockIdx.y, b = bh >> 3;
    const int tid = threadIdx.x;
    const int i0 = ic * 32;
    if (tid < 32) sS[tid] = s_src_t[bh * 1024 + i0 + tid];
    __syncthreads();

    // ---- pass 1: row denominators ----
    const int row = tid >> 3, c8 = tid & 7;
    const float ssr = sS[row];
    const size_t mrow = ((size_t)(b * 1024 + i0 + row)) << 10;
    float l = 0.f;
    #pragma unroll 4
    for (int q = 0; q < 32; q++) {
        const int j0 = c8 * 128 + q * 4;
        float4 s4 = *(const float4*)(s_tgt_t + bh * 1024 + j0);
        float sv[4] = {s4.x, s4.y, s4.z, s4.w};
        float mv[4];
        load_mask4(mask, mrow + j0, f32, mv);
        #pragma unroll
        for (int t = 0; t < 4; t++) {
            float x = ssr + sv[t];
            x = fmaxf(x, 0.2f * x);
            l += __expf(x + mv[t]);
        }
    }
    l += __shfl_xor(l, 1, 64);
    l += __shfl_xor(l, 2, 64);
    l += __shfl_xor(l, 4, 64);
    if (c8 == 0) sIl[row] = 1.0f / l;
    __syncthreads();

    // ---- pass 2: column partial sums ----
    const int j0 = tid * 4;
    float4 s4 = *(const float4*)(s_tgt_t + bh * 1024 + j0);
    float sv[4] = {s4.x, s4.y, s4.z, s4.w};
    float a[4] = {0.f, 0.f, 0.f, 0.f};
    for (int r = 0; r < 32; r++) {
        const float sr = sS[r], il = sIl[r];
        float mv[4];
        load_mask4(mask, (((size_t)(b * 1024 + i0 + r)) << 10) + j0, f32, mv);
        #pragma unroll
        for (int t = 0; t < 4; t++) {
            float x = sr + sv[t];
            x = fmaxf(x, 0.2f * x);
            a[t] = fmaf(il, __expf(x + mv[t]), a[t]);
        }
    }
    #pragma unroll
    for (int t = 0; t < 4; t++)
        atomicAdd(&c[bh * 1024 + j0 + t], a[t]);
}

// -------------------------------------------------------------------------
__global__ void zero_f(float* __restrict__ p, int n)
{
    int idx = blockIdx.x * blockDim.x + threadIdx.x;
    if (idx < n) p[idx] = 0.f;
}

// y[bh][k] += sum_{j in chunk} c[bh,j]*x2[b,j,k]; xbar[b][k] += sum_j x2[b,j,k]
__global__ __launch_bounds__(256) void yx_k(const bf16* __restrict__ x2,
                                            const float* __restrict__ c,
                                            float* __restrict__ y,
                                            float* __restrict__ xbar)
{
    __shared__ float sC[8][128];
    const int b = blockIdx.x, kt = blockIdx.y, jc = blockIdx.z;
    const int t = threadIdx.x;
    const int k = kt * 256 + t;
    const int j0 = jc * 128;
    for (int idx = t; idx < 8 * 128; idx += 256) {
        const int h = idx >> 7, jj = idx & 127;
        sC[h][jj] = c[(b * 8 + h) * 1024 + j0 + jj];
    }
    __syncthreads();
    float acc[8] = {0.f, 0.f, 0.f, 0.f, 0.f, 0.f, 0.f, 0.f};
    float ax = 0.f;
    for (int jj = 0; jj < 128; jj++) {
        const float xv = b2f(x2[((size_t)(b * 1024 + j0 + jj)) * 2048 + k]);
        ax += xv;
        #pragma unroll
        for (int h = 0; h < 8; h++) acc[h] = fmaf(sC[h][jj], xv, acc[h]);
    }
    #pragma unroll
    for (int h = 0; h < 8; h++)
        atomicAdd(&y[(b * 8 + h) * 2048 + k], acc[h]);
    atomicAdd(&xbar[b * 2048 + k], ax);
}

// gA[(b*8+h)][f] += sum_{k in chunk} y[b*8+h,k] * W2[k, h*256+f]; all 4 b per block.
__global__ __launch_bounds__(256) void gamat_k(const void* __restrict__ W2,
                                               const float* __restrict__ y,
                                               float* __restrict__ gA,
                                               const int* __restrict__ flag)
{
    __shared__ float sY[4][256];
    const int f32 = *flag;
    const int h = blockIdx.x, kc = blockIdx.y;
    const int f = threadIdx.x, k0 = kc * 256;
    for (int idx = threadIdx.x; idx < 1024; idx += 256) {
        const int bb = idx >> 8, kk = idx & 255;
        sY[bb][kk] = y[(bb * 8 + h) * 2048 + k0 + kk];
    }
    __syncthreads();
    float acc[4] = {0.f, 0.f, 0.f, 0.f};
    #pragma unroll 2
    for (int kk = 0; kk < 256; kk++) {
        const float w = loadf(W2, (size_t)(k0 + kk) * 2048 + h * 256 + f, f32);
        #pragma unroll
        for (int bb = 0; bb < 4; bb++) acc[bb] = fmaf(sY[bb][kk], w, acc[bb]);
    }
    #pragma unroll
    for (int bb = 0; bb < 4; bb++)
        atomicAdd(&gA[(bb * 8 + h) * 256 + f], acc[bb]);
}

// gS[b][hf] += sum_{k in chunk} xbar[b,k] * skip2[k,hf]; all 4 b per block.
__global__ __launch_bounds__(256) void skipvec_k(const void* __restrict__ skip2,
                                                 const float* __restrict__ xbar,
                                                 float* __restrict__ gS,
                                                 const int* __restrict__ flag)
{
    __shared__ float sX[4][256];
    const int f32 = *flag;
    const int hft = blockIdx.x, kc = blockIdx.y;
    const int hf = hft * 256 + threadIdx.x, k0 = kc * 256;
    for (int idx = threadIdx.x; idx < 1024; idx += 256) {
        const int bb = idx >> 8, kk = idx & 255;
        sX[bb][kk] = xbar[bb * 2048 + k0 + kk];
    }
    __syncthreads();
    float acc[4] = {0.f, 0.f, 0.f, 0.f};
    #pragma unroll 2
    for (int kk = 0; kk < 256; kk++) {
        const float w = loadf(skip2, (size_t)(k0 + kk) * 2048 + hf, f32);
        #pragma unroll
        for (int bb = 0; bb < 4; bb++) acc[bb] = fmaf(sX[bb][kk], w, acc[bb]);
    }
    #pragma unroll
    for (int bb = 0; bb < 4; bb++)
        atomicAdd(&gS[bb * 2048 + hf], acc[bb]);
}

// g[b,f] = (sum_h gA + sum_h gS)/(8*1024) + b2[f]; out = g@Wc + bc
__global__ __launch_bounds__(256) void classify2_k(const float* __restrict__ gA,
                                                   const float* __restrict__ gS,
                                                   const void* __restrict__ b2,
                                                   const void* __restrict__ Wc,
                                                   const void* __restrict__ bc,
                                                   void* __restrict__ out,
                                                   const int* __restrict__ flag)
{
    __shared__ float gv[256];
    const int f32 = *flag;
    const int b = blockIdx.x, f = threadIdx.x;
    float s = 0.f;
    #pragma unroll
    for (int h = 0; h < 8; h++)
        s += gA[(b * 8 + h) * 256 + f] + gS[b * 2048 + h * 256 + f];
    gv[f] = s * (1.0f / 8192.0f) + loadf(b2, f, f32);
    __syncthreads();
    if (f < 10) {
        float acc = loadf(bc, f, f32);
        for (int k = 0; k < 256; k++)
            acc = fmaf(gv[k], loadf(Wc, k * 10 + f, f32), acc);
        if (f32) ((float*)out)[b * 10 + f] = acc;
        else     ((bf16*)out)[b * 10 + f] = f2b(acc);
    }
}

// -------------------------------------------------------------------------
extern "C" void kernel_launch(void* const* d_in, const int* in_sizes, int n_in,
                              void* d_out, int out_size, void* d_ws, size_t ws_size,
                              hipStream_t stream)
{
    (void)in_sizes; (void)n_in; (void)out_size; (void)ws_size;
    const void* feat   = d_in[0];
    const void* mask   = d_in[2];
    const void* W1     = d_in[3];
    const void* a_src1 = d_in[4];
    const void* a_tgt1 = d_in[5];
    const void* skip1  = d_in[6];
    const void* b1     = d_in[7];
    const void* W2     = d_in[8];
    const void* a_src2 = d_in[9];
    const void* a_tgt2 = d_in[10];
    const void* skip2  = d_in[11];
    const void* b2v    = d_in[12];
    const void* Wc     = d_in[13];
    const void* bc     = d_in[14];

    char* ws = (char*)d_ws;
    size_t off = 0;
    auto alloc = [&](size_t bytes) -> void* {
        void* p = ws + off;
        off += (bytes + 255) & ~(size_t)255;
        return p;
    };
    int*   flag = (int*)alloc(256);
    bf16*  featc= (bf16*)alloc(4096ull * 256 * 2);
    bf16*  W1t  = (bf16*)alloc(2048ull * 256 * 2);
    bf16*  S1t  = (bf16*)alloc(2048ull * 256 * 2);
    bf16*  p1   = (bf16*)alloc(4096ull * 2048 * 2);
    bf16*  sk1  = (bf16*)alloc(4096ull * 2048 * 2);
    bf16*  x2   = (bf16*)alloc(4096ull * 2048 * 2);
    bf16*  pT   = (bf16*)alloc(4096ull * 2048 * 2);
    float* ss   = (float*)alloc(32ull * 1024 * 4);
    float* st   = (float*)alloc(32ull * 1024 * 4);
    float* Wa   = (float*)alloc(16ull * 2048 * 4);
    // cbuf, gA, gS, xbar, y contiguous: one zero_f covers all
    float* cbuf = (float*)alloc(32ull * 1024 * 4);     // 32768 floats
    float* gA   = (float*)alloc(32ull * 256 * 4);      // 8192
    float* gS   = (float*)alloc(4ull * 2048 * 4);      // 8192
    float* xbar = (float*)alloc(4ull * 2048 * 4);      // 8192
    float* y    = (float*)alloc(32ull * 2048 * 4);     // 65536

    detect_k<<<1, 64, 0, stream>>>(W1, flag);
    cvt_k<<<4096, 256, 0, stream>>>(feat, featc, 4096 * 256, flag);
    zero_f<<<480, 256, 0, stream>>>(cbuf, 32768 + 3 * 8192 + 65536);

    transpose_k<<<dim3(64, 8), 256, 0, stream>>>(W1,    W1t, 256, 2048, flag);
    transpose_k<<<dim3(64, 8), 256, 0, stream>>>(skip1, S1t, 256, 2048, flag);
    wproj_k<<<128, 256, 0, stream>>>(W2, a_src2, a_tgt2, Wa, flag);

    // ---- layer 1 ----
    gemm_bt2<<<dim3(16, 32, 2), 256, 0, stream>>>(featc, W1t, S1t, p1, sk1, 4096, 2048, 256);
    transpose_p<<<dim3(64, 32, 4), 256, 0, stream>>>(p1, pT);
    compute_sw<<<dim3(32, 256), 256, 0, stream>>>(p1, a_src1, a_tgt1, ss, st, flag);
    attn_fused<<<dim3(32, 32), 256, 0, stream>>>(ss, st, mask, pT, sk1, b1, x2, flag);

    // ---- layer 2 (fully collapsed) ----
    score2_k<<<4096, 256, 0, stream>>>(x2, Wa, ss, st);
    colsoft_k<<<dim3(32, 32), 256, 0, stream>>>(ss, st, mask, cbuf, flag);
    yx_k<<<dim3(4, 8, 8), 256, 0, stream>>>(x2, cbuf, y, xbar);
    gamat_k<<<dim3(8, 8), 256, 0, stream>>>(W2, y, gA, flag);
    skipvec_k<<<dim3(8, 8), 256, 0, stream>>>(skip2, xbar, gS, flag);

    // ---- classify ----
    classify2_k<<<4, 256, 0, stream>>>(gA, gS, b2v, Wc, bc, d_out, flag);
}

// Round 9
// 431.297 us; speedup vs baseline: 1.1692x; 1.1692x over previous
//
#include <hip/hip_runtime.h>
#include <hip/hip_bf16.h>
#include <stdint.h>
#include <stddef.h>

typedef __hip_bfloat16 bf16;
typedef __attribute__((ext_vector_type(8))) short bhalf8;
typedef __attribute__((ext_vector_type(4))) short short4v;
typedef __attribute__((ext_vector_type(4))) float floatx4;

static __device__ __forceinline__ float b2f(bf16 v) { return __bfloat162float(v); }
static __device__ __forceinline__ bf16  f2b(float v) { return __float2bfloat16(v); }
static __device__ __forceinline__ short f2s(float v) {
    union { bf16 b; short s; } u; u.b = __float2bfloat16(v); return u.s;
}

// dtype-agnostic scalar load: flag==1 -> fp32 data, flag==0 -> bf16 data
static __device__ __forceinline__ float loadf(const void* p, size_t i, int f32) {
    return f32 ? ((const float*)p)[i] : b2f(((const bf16*)p)[i]);
}

// async global->LDS, 16B per lane. LDS dest must be wave-uniform base + lane*16.
static __device__ __forceinline__ void gl_lds16(const void* g, void* l) {
    __builtin_amdgcn_global_load_lds(
        (const __attribute__((address_space(1))) void*)g,
        (__attribute__((address_space(3))) void*)l, 16, 0, 0);
}

// load 4 consecutive mask values at 4-aligned index
static __device__ __forceinline__ void load_mask4(const void* mask, size_t idx,
                                                  int f32, float* mv) {
    if (f32) {
        float4 v = *(const float4*)((const float*)mask + idx);
        mv[0] = v.x; mv[1] = v.y; mv[2] = v.z; mv[3] = v.w;
    } else {
        const bf16* p = (const bf16*)mask + idx;
        #pragma unroll
        for (int t = 0; t < 4; t++) mv[t] = b2f(p[t]);
    }
}

// -------------------------------------------------------------------------
__global__ void detect_k(const void* w1raw, int* flag)
{
    if (threadIdx.x == 0 && blockIdx.x == 0) {
        const unsigned short* s = (const unsigned short*)w1raw;
        int bad = 0;
        for (int i = 0; i < 256; i++) {
            int e = (s[i] >> 7) & 0xFF;
            if (e > 0x85 || (e != 0 && e < 0x60)) bad++;
        }
        *flag = (bad > 16) ? 1 : 0;
    }
}

__global__ __launch_bounds__(256) void cvt_k(const void* __restrict__ src,
                                             bf16* __restrict__ dst, int n,
                                             const int* __restrict__ flag)
{
    const int f = *flag;
    int i = blockIdx.x * 256 + threadIdx.x;
    if (i < n) dst[i] = f ? f2b(((const float*)src)[i]) : ((const bf16*)src)[i];
}

// -------------------------------------------------------------------------
__global__ __launch_bounds__(256) void transpose_k(const void* __restrict__ in,
                                                   bf16* __restrict__ out,
                                                   int R, int C,
                                                   const int* __restrict__ flag)
{
    __shared__ bf16 tile[32][33];
    const int f = *flag;
    const int tx = threadIdx.x & 31;
    const int ty = threadIdx.x >> 5;
    const int c0 = blockIdx.x * 32;
    const int r0 = blockIdx.y * 32;
    #pragma unroll
    for (int yy = ty; yy < 32; yy += 8)
        tile[yy][tx] = f2b(loadf(in, (size_t)(r0 + yy) * C + c0 + tx, f));
    __syncthreads();
    #pragma unroll
    for (int yy = ty; yy < 32; yy += 8)
        out[(size_t)(c0 + yy) * R + r0 + tx] = tile[tx][yy];
}

// batched bf16 transpose: per b, in (1024 x 2048) -> out (2048 x 1024)
__global__ __launch_bounds__(256) void transpose_p(const bf16* __restrict__ in,
                                                   bf16* __restrict__ out)
{
    __shared__ bf16 tile[32][33];
    const int bz = blockIdx.z;
    const int tx = threadIdx.x & 31;
    const int ty = threadIdx.x >> 5;
    const int c0 = blockIdx.x * 32;
    const int r0 = blockIdx.y * 32;
    const bf16* ib = in + (size_t)bz * 1024 * 2048;
    bf16* ob = out + (size_t)bz * 1024 * 2048;
    #pragma unroll
    for (int yy = ty; yy < 32; yy += 8)
        tile[yy][tx] = ib[(size_t)(r0 + yy) * 2048 + c0 + tx];
    __syncthreads();
    #pragma unroll
    for (int yy = ty; yy < 32; yy += 8)
        ob[(size_t)(c0 + yy) * 1024 + r0 + tx] = tile[tx][yy];
}

// -------------------------------------------------------------------------
// Paired GEMM (layer 1): C = A@B[z]. m97 structure.
__global__ __launch_bounds__(256) void gemm_bt2(const bf16* __restrict__ A,
                                                const bf16* __restrict__ Bt0,
                                                const bf16* __restrict__ Bt1,
                                                bf16* __restrict__ C0,
                                                bf16* __restrict__ C1,
                                                int M, int N, int K)
{
    __shared__ __align__(16) short sA[128][32];
    __shared__ __align__(16) short sB[128][32];
    const int tid  = threadIdx.x;
    const int bx   = blockIdx.x, by = blockIdx.y;
    const bf16* Bt = blockIdx.z ? Bt1 : Bt0;
    bf16* C        = blockIdx.z ? C1  : C0;
    const int wave = tid >> 6, lane = tid & 63;
    const int wm   = wave >> 1, wn = wave & 1;
    const int lrow = lane & 15, quad = lane >> 4;

    floatx4 acc[4][4];
    #pragma unroll
    for (int i = 0; i < 4; i++)
        #pragma unroll
        for (int j = 0; j < 4; j++)
            acc[i][j] = (floatx4){0.f, 0.f, 0.f, 0.f};

    const int srow = wave * 32 + (lane >> 2);
    const int scol = (lane & 3) * 8;
    const bf16* gA0 = A  + (size_t)(by * 128 + srow) * K + scol;
    const bf16* gA1 = gA0 + (size_t)16 * K;
    const bf16* gB0 = Bt + (size_t)(bx * 128 + srow) * K + scol;
    const bf16* gB1 = gB0 + (size_t)16 * K;
    char* lA0 = (char*)&sA[0][0] + wave * 2048 + lane * 16;
    char* lA1 = lA0 + 1024;
    char* lB0 = (char*)&sB[0][0] + wave * 2048 + lane * 16;
    char* lB1 = lB0 + 1024;

    for (int k0 = 0; k0 < K; k0 += 32) {
        __syncthreads();
        gl_lds16(gA0 + k0, lA0);
        gl_lds16(gA1 + k0, lA1);
        gl_lds16(gB0 + k0, lB0);
        gl_lds16(gB1 + k0, lB1);
        __syncthreads();
        bhalf8 af[4], bfr[4];
        #pragma unroll
        for (int t = 0; t < 4; t++) af[t]  = *(const bhalf8*)&sA[wm * 64 + t * 16 + lrow][quad * 8];
        #pragma unroll
        for (int t = 0; t < 4; t++) bfr[t] = *(const bhalf8*)&sB[wn * 64 + t * 16 + lrow][quad * 8];
        #pragma unroll
        for (int tm = 0; tm < 4; tm++)
            #pragma unroll
            for (int tn = 0; tn < 4; tn++)
                acc[tm][tn] = __builtin_amdgcn_mfma_f32_16x16x32_bf16(af[tm], bfr[tn], acc[tm][tn], 0, 0, 0);
    }

    #pragma unroll
    for (int tm = 0; tm < 4; tm++) {
        #pragma unroll
        for (int tn = 0; tn < 4; tn++) {
            const int col = bx * 128 + wn * 64 + tn * 16 + lrow;
            #pragma unroll
            for (int r = 0; r < 4; r++) {
                const int row = by * 128 + wm * 64 + tm * 16 + quad * 4 + r;
                C[(size_t)row * N + col] = f2b(acc[tm][tn][r]);
            }
        }
    }
}

// -------------------------------------------------------------------------
// s_src/s_tgt for layer 1: wave-autonomous dot over f=256.
__global__ __launch_bounds__(256) void compute_sw(const bf16* __restrict__ p,
                                                  const void* __restrict__ a_src,
                                                  const void* __restrict__ a_tgt,
                                                  float* __restrict__ s_src_t,
                                                  float* __restrict__ s_tgt_t,
                                                  const int* __restrict__ flag)
{
    const int f32 = *flag;
    const int bh = blockIdx.x, b = bh >> 3, h = bh & 7;
    const int wave = threadIdx.x >> 6, lane = threadIdx.x & 63;
    const int n = blockIdx.y * 4 + wave;
    const bf16* pr = p + ((size_t)(b * 1024 + n)) * 2048 + h * 256;
    float ss = 0.f, st = 0.f;
    #pragma unroll
    for (int q = 0; q < 4; q++) {
        const int f = q * 64 + lane;
        float pv = b2f(pr[f]);
        ss = fmaf(pv, loadf(a_src, h * 256 + f, f32), ss);
        st = fmaf(pv, loadf(a_tgt, h * 256 + f, f32), st);
    }
    #pragma unroll
    for (int off = 32; off; off >>= 1) {
        ss += __shfl_down(ss, off, 64);
        st += __shfl_down(st, off, 64);
    }
    if (lane == 0) {
        s_src_t[bh * 1024 + n] = ss;
        s_tgt_t[bh * 1024 + n] = st;
    }
}

// -------------------------------------------------------------------------
// Fused layer-1 attention v3: 32x256 tile, BK=32, dbuf, s_tgt LDS-cached
// (bf16), mask register-prefetched ONE ITERATION AHEAD so no global latency
// sits in the exp->LDS->barrier chain.
__global__ __launch_bounds__(256) void attn_fused(const float* __restrict__ s_src_t,
                                                  const float* __restrict__ s_tgt_t,
                                                  const void* __restrict__ mask,
                                                  const bf16* __restrict__ pT,
                                                  const bf16* __restrict__ sk,
                                                  const void* __restrict__ bias,
                                                  bf16* __restrict__ x2,
                                                  const int* __restrict__ flag)
{
    __shared__ __align__(16) short sA[2][32][32];    // exp numerators
    __shared__ __align__(16) short sB[2][256][32];   // pT tile (f x k)
    __shared__ short sStgt[1024];                    // s_tgt (bf16)
    __shared__ float sInvl[32];

    const int tid = threadIdx.x;
    const int by = blockIdx.x, bh = blockIdx.y;
    const int b = bh >> 3, h = bh & 7;
    const int f32 = *flag;
    const int wave = tid >> 6, lane = tid & 63;
    const int lrow = lane & 15, quad = lane >> 4;

    // cache s_tgt as bf16 (keeps LDS < 40 KB -> 4 blocks/CU)
    #pragma unroll
    for (int q = 0; q < 4; q++)
        sStgt[q * 256 + tid] = f2s(s_tgt_t[bh * 1024 + q * 256 + tid]);

    // exp-gen assignment: 8 threads per row, 4 cols each
    const int row  = tid >> 3;            // 0..31
    const int col0 = (tid & 7) * 4;       // 0..28
    const float ssr = s_src_t[bh * 1024 + by * 32 + row];
    const size_t mrow0 = ((size_t)(b * 1024 + by * 32 + row)) << 10;

    // B staging: thread covers f-row tid>>2 (+64c), k-cols (tid&3)*8..+7
    const bf16* gB = pT + ((size_t)bh << 18) + (size_t)(tid >> 2) * 1024 + (tid & 3) * 8;

    floatx4 acc[2][4];
    #pragma unroll
    for (int i = 0; i < 2; i++)
        #pragma unroll
        for (int j = 0; j < 4; j++)
            acc[i][j] = (floatx4){0.f, 0.f, 0.f, 0.f};

    float lacc = 0.f;

    auto stageB = [&](int k0, int buf) {
        const bf16* g = gB + k0;
        char* l = (char*)&sB[buf][0][0] + tid * 16;
        #pragma unroll
        for (int c = 0; c < 4; c++)
            gl_lds16(g + (size_t)(64 * c) * 1024, l + c * 4096);
    };
    // generate exp tile k0 using PRE-LOADED mask values mv (regs) + LDS s_tgt
    auto genA = [&](int k0, int buf, const float* mv) {
        const short* sp = &sStgt[k0 + col0];
        short4v ev;
        #pragma unroll
        for (int t = 0; t < 4; t++) {
            union { short s; bf16 b; } u; u.s = sp[t];
            float x = ssr + b2f(u.b);
            x = fmaxf(x, 0.2f * x);          // leaky_relu(0.2)
            float e = __expf(x + mv[t]);
            lacc += e;
            ev[t] = f2s(e);
        }
        *(short4v*)&sA[buf][row][col0] = ev;
    };

    // ---- prologue ----
    float mv[4];
    stageB(0, 0);
    load_mask4(mask, mrow0 + col0, f32, mv);         // mask tile 0
    __syncthreads();                                 // sStgt visible; drains prologue loads
    genA(0, 0, mv);                                  // tile 0 -> A[0]
    load_mask4(mask, mrow0 + 32 + col0, f32, mv);    // prefetch mask tile 1

    int cur = 0;
    for (int k0 = 0; k0 < 1024; k0 += 32, cur ^= 1) {
        __syncthreads();                 // A[cur], B[cur] ready
        if (k0 + 32 < 1024) {
            const int nxt = cur ^ 1;
            stageB(k0 + 32, nxt);        // async B for next iter
            genA(k0 + 32, nxt, mv);      // exps from prefetched mask (regs only)
            if (k0 + 64 < 1024)
                load_mask4(mask, mrow0 + k0 + 64 + col0, f32, mv);  // prefetch
        }
        bhalf8 af[2], bfr[4];
        #pragma unroll
        for (int mt = 0; mt < 2; mt++)
            af[mt] = *(const bhalf8*)&sA[cur][mt * 16 + lrow][quad * 8];
        #pragma unroll
        for (int nt = 0; nt < 4; nt++)
            bfr[nt] = *(const bhalf8*)&sB[cur][wave * 64 + nt * 16 + lrow][quad * 8];
        #pragma unroll
        for (int mt = 0; mt < 2; mt++)
            #pragma unroll
            for (int nt = 0; nt < 4; nt++)
                acc[mt][nt] = __builtin_amdgcn_mfma_f32_16x16x32_bf16(af[mt], bfr[nt], acc[mt][nt], 0, 0, 0);
    }

    // row denominators: 8 consecutive lanes share a row
    lacc += __shfl_xor(lacc, 1, 64);
    lacc += __shfl_xor(lacc, 2, 64);
    lacc += __shfl_xor(lacc, 4, 64);
    if ((tid & 7) == 0) sInvl[row] = 1.0f / lacc;
    __syncthreads();

    #pragma unroll
    for (int mt = 0; mt < 2; mt++) {
        #pragma unroll
        for (int r = 0; r < 4; r++) {
            const int rl = mt * 16 + quad * 4 + r;          // 0..31
            const int rg = by * 32 + rl;
            const float il = sInvl[rl];
            #pragma unroll
            for (int nt = 0; nt < 4; nt++) {
                const int col = wave * 64 + nt * 16 + lrow; // 0..255
                const int hf = h * 256 + col;
                const size_t idx = ((size_t)(b * 1024 + rg)) * 2048 + hf;
                float v = acc[mt][nt][r] * il + b2f(sk[idx]) + loadf(bias, hf, f32);
                v = (v > 0.f) ? v : expm1f(v);     // ELU
                x2[idx] = f2b(v);
            }
        }
    }
}

// -------------------------------------------------------------------------
// Wa[hh][k] = sum_f W2[k, h*256+f] * a[h][f], hh 0..7 = a_src2, 8..15 = a_tgt2.
__global__ __launch_bounds__(256) void wproj_k(const void* __restrict__ W2,
                                               const void* __restrict__ a_src2,
                                               const void* __restrict__ a_tgt2,
                                               float* __restrict__ Wa,
                                               const int* __restrict__ flag)
{
    __shared__ float sa[256];
    const int f32 = *flag;
    const int id = blockIdx.x * 256 + threadIdx.x;   // 0..32767
    const int hh = id >> 11, k = id & 2047, h = hh & 7;
    const void* a = (hh < 8) ? a_src2 : a_tgt2;
    sa[threadIdx.x] = loadf(a, h * 256 + threadIdx.x, f32);
    __syncthreads();
    float acc = 0.f;
    #pragma unroll 4
    for (int f = 0; f < 256; f++)
        acc = fmaf(loadf(W2, (size_t)k * 2048 + h * 256 + f, f32), sa[f], acc);
    Wa[hh * 2048 + k] = acc;
}

// -------------------------------------------------------------------------
// Layer-2 scores: ss/st[bh][n] = sum_k x2[b,n,k] * Wa[hh][k]. Block per node.
__global__ __launch_bounds__(256) void score2_k(const bf16* __restrict__ x2,
                                                const float* __restrict__ Wa,
                                                float* __restrict__ s_src_t,
                                                float* __restrict__ s_tgt_t)
{
    const int bid = blockIdx.x;           // b*1024 + n
    const int b = bid >> 10, n = bid & 1023;
    const int wave = threadIdx.x >> 6, lane = threadIdx.x & 63;
    const bf16* xr = x2 + (size_t)bid * 2048;
    float xv[32];
    #pragma unroll
    for (int q = 0; q < 32; q++) xv[q] = b2f(xr[q * 64 + lane]);
    #pragma unroll
    for (int c = 0; c < 4; c++) {
        const int hh = c * 4 + wave;      // 0..15
        const float* wr = Wa + hh * 2048;
        float acc = 0.f;
        #pragma unroll
        for (int q = 0; q < 32; q++) acc = fmaf(xv[q], wr[q * 64 + lane], acc);
        #pragma unroll
        for (int off = 32; off; off >>= 1) acc += __shfl_down(acc, off, 64);
        if (lane == 0) {
            if (hh < 8) s_src_t[(b * 8 + hh) * 1024 + n] = acc;
            else        s_tgt_t[(b * 8 + hh - 8) * 1024 + n] = acc;
        }
    }
}

// -------------------------------------------------------------------------
// Layer-2 denominators. Wave handles h=wave, wave+4.  (R7 version)
__global__ __launch_bounds__(256) void lpass_k(const float* __restrict__ s_src_t,
                                               const float* __restrict__ s_tgt_t,
                                               const void* __restrict__ mask,
                                               float* __restrict__ invl,
                                               const int* __restrict__ flag)
{
    const int f32 = *flag;
    const int b = blockIdx.x >> 7, itile = blockIdx.x & 127;
    const int wave = threadIdx.x >> 6, lane = threadIdx.x & 63;
    const int h0 = wave, h1 = wave + 4;
    float st0[16], st1[16];
    #pragma unroll
    for (int q = 0; q < 16; q++) {
        st0[q] = s_tgt_t[(b * 8 + h0) * 1024 + q * 64 + lane];
        st1[q] = s_tgt_t[(b * 8 + h1) * 1024 + q * 64 + lane];
    }
    for (int r = 0; r < 8; r++) {
        const int i = itile * 8 + r;
        const size_t moff = ((size_t)b * 1024 + i) * 1024;
        float mrow[16];
        #pragma unroll
        for (int q = 0; q < 16; q++) mrow[q] = loadf(mask, moff + q * 64 + lane, f32);
        #pragma unroll
        for (int hh = 0; hh < 2; hh++) {
            const int h = hh ? h1 : h0;
            const float ssr = s_src_t[(b * 8 + h) * 1024 + i];
            float l = 0.f;
            #pragma unroll
            for (int q = 0; q < 16; q++) {
                float x = ssr + (hh ? st1[q] : st0[q]);
                x = (x > 0.f) ? x : 0.2f * x;
                l += __expf(x + mrow[q]);
            }
            #pragma unroll
            for (int off = 32; off; off >>= 1) l += __shfl_down(l, off, 64);
            if (lane == 0) invl[(b * 8 + h) * 1024 + i] = 1.0f / l;
        }
    }
}

// -------------------------------------------------------------------------
// c[bh][j] += sum_{i in chunk} invl[i]*e[i,j], e regenerated inline. (R7)
__global__ __launch_bounds__(256) void colsum2_k(const float* __restrict__ s_src_t,
                                                 const float* __restrict__ s_tgt_t,
                                                 const void* __restrict__ mask,
                                                 const float* __restrict__ invl,
                                                 float* __restrict__ c,
                                                 const int* __restrict__ flag)
{
    __shared__ float sS[256], sIl[256];
    const int f32 = *flag;
    const int bh = blockIdx.x, b = bh >> 3;
    const int j = blockIdx.y * 256 + threadIdx.x;
    const int i0 = blockIdx.z * 256;
    sS[threadIdx.x]  = s_src_t[bh * 1024 + i0 + threadIdx.x];
    sIl[threadIdx.x] = invl[bh * 1024 + i0 + threadIdx.x];
    __syncthreads();
    const float stj = s_tgt_t[bh * 1024 + j];
    float acc = 0.f;
    #pragma unroll 4
    for (int ii = 0; ii < 256; ii++) {
        float x = sS[ii] + stj;
        x = (x > 0.f) ? x : 0.2f * x;
        float e = __expf(x + loadf(mask, (((size_t)(b * 1024 + i0 + ii)) << 10) + j, f32));
        acc = fmaf(sIl[ii], e, acc);
    }
    atomicAdd(&c[bh * 1024 + j], acc);
}

// -------------------------------------------------------------------------
__global__ void zero_f(float* __restrict__ p, int n)
{
    int idx = blockIdx.x * blockDim.x + threadIdx.x;
    if (idx < n) p[idx] = 0.f;
}

// y[bh][k] += sum_{j in chunk} c[bh,j]*x2[b,j,k]; xbar[b][k] += sum_j x2[b,j,k]
__global__ __launch_bounds__(256) void yx_k(const bf16* __restrict__ x2,
                                            const float* __restrict__ c,
                                            float* __restrict__ y,
                                            float* __restrict__ xbar)
{
    __shared__ float sC[8][128];
    const int b = blockIdx.x, kt = blockIdx.y, jc = blockIdx.z;
    const int t = threadIdx.x;
    const int k = kt * 256 + t;
    const int j0 = jc * 128;
    for (int idx = t; idx < 8 * 128; idx += 256) {
        const int h = idx >> 7, jj = idx & 127;
        sC[h][jj] = c[(b * 8 + h) * 1024 + j0 + jj];
    }
    __syncthreads();
    float acc[8] = {0.f, 0.f, 0.f, 0.f, 0.f, 0.f, 0.f, 0.f};
    float ax = 0.f;
    for (int jj = 0; jj < 128; jj++) {
        const float xv = b2f(x2[((size_t)(b * 1024 + j0 + jj)) * 2048 + k]);
        ax += xv;
        #pragma unroll
        for (int h = 0; h < 8; h++) acc[h] = fmaf(sC[h][jj], xv, acc[h]);
    }
    #pragma unroll
    for (int h = 0; h < 8; h++)
        atomicAdd(&y[(b * 8 + h) * 2048 + k], acc[h]);
    atomicAdd(&xbar[b * 2048 + k], ax);
}

// gA[bh][f] += sum_{k in chunk} y[bh,k] * W2[k, h*256+f]   (R7 grid 32x8)
__global__ __launch_bounds__(256) void gamat_k(const void* __restrict__ W2,
                                               const float* __restrict__ y,
                                               float* __restrict__ gA,
                                               const int* __restrict__ flag)
{
    __shared__ float sY[256];
    const int f32 = *flag;
    const int bh = blockIdx.x, kc = blockIdx.y;
    const int h = bh & 7, f = threadIdx.x;
    const int k0 = kc * 256;
    sY[threadIdx.x] = y[bh * 2048 + k0 + threadIdx.x];
    __syncthreads();
    float acc = 0.f;
    #pragma unroll 4
    for (int kk = 0; kk < 256; kk++)
        acc = fmaf(sY[kk], loadf(W2, (size_t)(k0 + kk) * 2048 + h * 256 + f, f32), acc);
    atomicAdd(&gA[bh * 256 + f], acc);
}

// gS[b][hf] += sum_{k in chunk} xbar[b,k] * skip2[k,hf]   (R7 grid 4x8x8)
__global__ __launch_bounds__(256) void skipvec_k(const void* __restrict__ skip2,
                                                 const float* __restrict__ xbar,
                                                 float* __restrict__ gS,
                                                 const int* __restrict__ flag)
{
    const int f32 = *flag;
    const int b = blockIdx.x, hft = blockIdx.y, kc = blockIdx.z;
    const int hf = hft * 256 + threadIdx.x;
    float acc = 0.f;
    #pragma unroll 4
    for (int kk = 0; kk < 256; kk++) {
        const int k = kc * 256 + kk;
        acc = fmaf(xbar[b * 2048 + k], loadf(skip2, (size_t)k * 2048 + hf, f32), acc);
    }
    atomicAdd(&gS[b * 2048 + hf], acc);
}

// g[b,f] = (sum_h gA + sum_h gS)/(8*1024) + b2[f]; out = g@Wc + bc
__global__ __launch_bounds__(256) void classify2_k(const float* __restrict__ gA,
                                                   const float* __restrict__ gS,
                                                   const void* __restrict__ b2,
                                                   const void* __restrict__ Wc,
                                                   const void* __restrict__ bc,
                                                   void* __restrict__ out,
                                                   const int* __restrict__ flag)
{
    __shared__ float gv[256];
    const int f32 = *flag;
    const int b = blockIdx.x, f = threadIdx.x;
    float s = 0.f;
    #pragma unroll
    for (int h = 0; h < 8; h++)
        s += gA[(b * 8 + h) * 256 + f] + gS[b * 2048 + h * 256 + f];
    gv[f] = s * (1.0f / 8192.0f) + loadf(b2, f, f32);
    __syncthreads();
    if (f < 10) {
        float acc = loadf(bc, f, f32);
        for (int k = 0; k < 256; k++)
            acc = fmaf(gv[k], loadf(Wc, k * 10 + f, f32), acc);
        if (f32) ((float*)out)[b * 10 + f] = acc;
        else     ((bf16*)out)[b * 10 + f] = f2b(acc);
    }
}

// -------------------------------------------------------------------------
extern "C" void kernel_launch(void* const* d_in, const int* in_sizes, int n_in,
                              void* d_out, int out_size, void* d_ws, size_t ws_size,
                              hipStream_t stream)
{
    (void)in_sizes; (void)n_in; (void)out_size; (void)ws_size;
    const void* feat   = d_in[0];
    const void* mask   = d_in[2];
    const void* W1     = d_in[3];
    const void* a_src1 = d_in[4];
    const void* a_tgt1 = d_in[5];
    const void* skip1  = d_in[6];
    const void* b1     = d_in[7];
    const void* W2     = d_in[8];
    const void* a_src2 = d_in[9];
    const void* a_tgt2 = d_in[10];
    const void* skip2  = d_in[11];
    const void* b2v    = d_in[12];
    const void* Wc     = d_in[13];
    const void* bc     = d_in[14];

    char* ws = (char*)d_ws;
    size_t off = 0;
    auto alloc = [&](size_t bytes) -> void* {
        void* p = ws + off;
        off += (bytes + 255) & ~(size_t)255;
        return p;
    };
    int*   flag = (int*)alloc(256);
    bf16*  featc= (bf16*)alloc(4096ull * 256 * 2);
    bf16*  W1t  = (bf16*)alloc(2048ull * 256 * 2);
    bf16*  S1t  = (bf16*)alloc(2048ull * 256 * 2);
    bf16*  p1   = (bf16*)alloc(4096ull * 2048 * 2);
    bf16*  sk1  = (bf16*)alloc(4096ull * 2048 * 2);
    bf16*  x2   = (bf16*)alloc(4096ull * 2048 * 2);
    bf16*  pT   = (bf16*)alloc(4096ull * 2048 * 2);
    float* invl = (float*)alloc(32ull * 1024 * 4);
    float* ss   = (float*)alloc(32ull * 1024 * 4);
    float* st   = (float*)alloc(32ull * 1024 * 4);
    float* Wa   = (float*)alloc(16ull * 2048 * 4);
    // cbuf, gA, gS, xbar, y contiguous: one zero_f covers all
    float* cbuf = (float*)alloc(32ull * 1024 * 4);     // 32768 floats
    float* gA   = (float*)alloc(32ull * 256 * 4);      // 8192
    float* gS   = (float*)alloc(4ull * 2048 * 4);      // 8192
    float* xbar = (float*)alloc(4ull * 2048 * 4);      // 8192
    float* y    = (float*)alloc(32ull * 2048 * 4);     // 65536

    detect_k<<<1, 64, 0, stream>>>(W1, flag);
    cvt_k<<<4096, 256, 0, stream>>>(feat, featc, 4096 * 256, flag);
    zero_f<<<480, 256, 0, stream>>>(cbuf, 32768 + 3 * 8192 + 65536);

    transpose_k<<<dim3(64, 8), 256, 0, stream>>>(W1,    W1t, 256, 2048, flag);
    transpose_k<<<dim3(64, 8), 256, 0, stream>>>(skip1, S1t, 256, 2048, flag);
    wproj_k<<<128, 256, 0, stream>>>(W2, a_src2, a_tgt2, Wa, flag);

    // ---- layer 1 ----
    gemm_bt2<<<dim3(16, 32, 2), 256, 0, stream>>>(featc, W1t, S1t, p1, sk1, 4096, 2048, 256);
    transpose_p<<<dim3(64, 32, 4), 256, 0, stream>>>(p1, pT);
    compute_sw<<<dim3(32, 256), 256, 0, stream>>>(p1, a_src1, a_tgt1, ss, st, flag);
    attn_fused<<<dim3(32, 32), 256, 0, stream>>>(ss, st, mask, pT, sk1, b1, x2, flag);

    // ---- layer 2 (fully collapsed) ----
    score2_k<<<4096, 256, 0, stream>>>(x2, Wa, ss, st);
    lpass_k<<<512, 256, 0, stream>>>(ss, st, mask, invl, flag);
    colsum2_k<<<dim3(32, 4, 4), 256, 0, stream>>>(ss, st, mask, invl, cbuf, flag);
    yx_k<<<dim3(4, 8, 8), 256, 0, stream>>>(x2, cbuf, y, xbar);
    gamat_k<<<dim3(32, 8), 256, 0, stream>>>(W2, y, gA, flag);
    skipvec_k<<<dim3(4, 8, 8), 256, 0, stream>>>(skip2, xbar, gS, flag);

    // ---- classify ----
    classify2_k<<<4, 256, 0, stream>>>(gA, gS, b2v, Wc, bc, d_out, flag);
}

// Round 10
// 414.656 us; speedup vs baseline: 1.2161x; 1.0401x over previous
//
#include <hip/hip_runtime.h>
#include <hip/hip_bf16.h>
#include <stdint.h>
#include <stddef.h>

typedef __hip_bfloat16 bf16;
typedef __attribute__((ext_vector_type(8))) short bhalf8;
typedef __attribute__((ext_vector_type(4))) short short4v;
typedef __attribute__((ext_vector_type(4))) float floatx4;

static __device__ __forceinline__ float b2f(bf16 v) { return __bfloat162float(v); }
static __device__ __forceinline__ bf16  f2b(float v) { return __float2bfloat16(v); }
static __device__ __forceinline__ short f2s(float v) {
    union { bf16 b; short s; } u; u.b = __float2bfloat16(v); return u.s;
}

// dtype-agnostic scalar load: flag==1 -> fp32 data, flag==0 -> bf16 data
static __device__ __forceinline__ float loadf(const void* p, size_t i, int f32) {
    return f32 ? ((const float*)p)[i] : b2f(((const bf16*)p)[i]);
}

// async global->LDS, 16B per lane. LDS dest must be wave-uniform base + lane*16.
static __device__ __forceinline__ void gl_lds16(const void* g, void* l) {
    __builtin_amdgcn_global_load_lds(
        (const __attribute__((address_space(1))) void*)g,
        (__attribute__((address_space(3))) void*)l, 16, 0, 0);
}

// load 4 consecutive mask values at 4-aligned index
static __device__ __forceinline__ void load_mask4(const void* mask, size_t idx,
                                                  int f32, float* mv) {
    if (f32) {
        float4 v = *(const float4*)((const float*)mask + idx);
        mv[0] = v.x; mv[1] = v.y; mv[2] = v.z; mv[3] = v.w;
    } else {
        const bf16* p = (const bf16*)mask + idx;
        #pragma unroll
        for (int t = 0; t < 4; t++) mv[t] = b2f(p[t]);
    }
}

// -------------------------------------------------------------------------
// Fused prep: inline dtype-detect + [cvt feat | zero accumulators |
// transpose W1 | transpose skip1 | wproj]. One dispatch replaces six.
// Segments: [0,4096) cvt, [4096,4576) zero, [4576,5088) T(W1),
// [5088,5600) T(skip1), [5600,5728) wproj.
__global__ __launch_bounds__(256) void prep_k(const void* __restrict__ feat,
                                              bf16* __restrict__ featc,
                                              float* __restrict__ zbase, int nzero,
                                              const void* __restrict__ W1,
                                              bf16* __restrict__ W1t,
                                              const void* __restrict__ skip1,
                                              bf16* __restrict__ S1t,
                                              const void* __restrict__ W2,
                                              const void* __restrict__ a_src2,
                                              const void* __restrict__ a_tgt2,
                                              float* __restrict__ Wa,
                                              int* __restrict__ flagp)
{
    __shared__ int sflag;
    __shared__ bf16 tile[32][33];
    const int tid = threadIdx.x;

    // inline dtype detection from W1 raw bits (values ~ N(0,0.05))
    if (tid < 64) {
        const unsigned short* s = (const unsigned short*)W1;
        int bad = 0;
        #pragma unroll
        for (int i = 0; i < 4; i++) {
            int e = (s[tid * 4 + i] >> 7) & 0xFF;
            if (e > 0x85 || (e != 0 && e < 0x60)) bad++;
        }
        bad += __shfl_xor(bad, 1, 64);
        bad += __shfl_xor(bad, 2, 64);
        bad += __shfl_xor(bad, 4, 64);
        bad += __shfl_xor(bad, 8, 64);
        bad += __shfl_xor(bad, 16, 64);
        bad += __shfl_xor(bad, 32, 64);
        if (tid == 0) sflag = (bad > 16) ? 1 : 0;
    }
    __syncthreads();
    const int f32 = sflag;

    int id = blockIdx.x;
    if (id == 0 && tid == 0) *flagp = f32;     // publish for later dispatches

    if (id < 4096) {                           // ---- cvt feat -> bf16 ----
        const int i = id * 256 + tid;
        featc[i] = f32 ? f2b(((const float*)feat)[i]) : ((const bf16*)feat)[i];
        return;
    }
    id -= 4096;
    if (id < 480) {                            // ---- zero accumulators ----
        const int i = id * 256 + tid;
        if (i < nzero) zbase[i] = 0.f;
        return;
    }
    id -= 480;
    if (id < 1024) {                           // ---- transposes (256x2048) ----
        const void* in = (id < 512) ? W1 : skip1;
        bf16* out = (id < 512) ? W1t : S1t;
        const int t = id & 511;
        const int bx = t & 63, byy = t >> 6;
        const int tx = tid & 31, ty = tid >> 5;
        const int c0 = bx * 32, r0 = byy * 32;
        #pragma unroll
        for (int yy = ty; yy < 32; yy += 8)
            tile[yy][tx] = f2b(loadf(in, (size_t)(r0 + yy) * 2048 + c0 + tx, f32));
        __syncthreads();
        #pragma unroll
        for (int yy = ty; yy < 32; yy += 8)
            out[(size_t)(c0 + yy) * 256 + r0 + tx] = tile[tx][yy];
        return;
    }
    id -= 1024;
    // ---- wproj: Wa[hh*2048+k] = sum_f W2[k, h*256+f]*a[h][f] ----
    // block covers 256 consecutive outputs (hh constant); wave-per-output,
    // lanes over f (coalesced).
    {
        const int wave = tid >> 6, lane = tid & 63;
        const int base = id * 256;
        const int hh = base >> 11, h = hh & 7;
        const void* a = (hh < 8) ? a_src2 : a_tgt2;
        float av[4];
        #pragma unroll
        for (int i = 0; i < 4; i++) av[i] = loadf(a, h * 256 + lane * 4 + i, f32);
        for (int o = 0; o < 64; o++) {
            const int idx = base + wave * 64 + o;
            const int k = idx & 2047;
            float acc = 0.f;
            #pragma unroll
            for (int i = 0; i < 4; i++)
                acc = fmaf(loadf(W2, (size_t)k * 2048 + h * 256 + lane * 4 + i, f32),
                           av[i], acc);
            #pragma unroll
            for (int off2 = 32; off2; off2 >>= 1) acc += __shfl_down(acc, off2, 64);
            if (lane == 0) Wa[idx] = acc;
        }
    }
}

// -------------------------------------------------------------------------
// Paired GEMM (layer 1): C = A@B[z]. m97 structure. (unchanged R9)
__global__ __launch_bounds__(256) void gemm_bt2(const bf16* __restrict__ A,
                                                const bf16* __restrict__ Bt0,
                                                const bf16* __restrict__ Bt1,
                                                bf16* __restrict__ C0,
                                                bf16* __restrict__ C1,
                                                int M, int N, int K)
{
    __shared__ __align__(16) short sA[128][32];
    __shared__ __align__(16) short sB[128][32];
    const int tid  = threadIdx.x;
    const int bx   = blockIdx.x, by = blockIdx.y;
    const bf16* Bt = blockIdx.z ? Bt1 : Bt0;
    bf16* C        = blockIdx.z ? C1  : C0;
    const int wave = tid >> 6, lane = tid & 63;
    const int wm   = wave >> 1, wn = wave & 1;
    const int lrow = lane & 15, quad = lane >> 4;

    floatx4 acc[4][4];
    #pragma unroll
    for (int i = 0; i < 4; i++)
        #pragma unroll
        for (int j = 0; j < 4; j++)
            acc[i][j] = (floatx4){0.f, 0.f, 0.f, 0.f};

    const int srow = wave * 32 + (lane >> 2);
    const int scol = (lane & 3) * 8;
    const bf16* gA0 = A  + (size_t)(by * 128 + srow) * K + scol;
    const bf16* gA1 = gA0 + (size_t)16 * K;
    const bf16* gB0 = Bt + (size_t)(bx * 128 + srow) * K + scol;
    const bf16* gB1 = gB0 + (size_t)16 * K;
    char* lA0 = (char*)&sA[0][0] + wave * 2048 + lane * 16;
    char* lA1 = lA0 + 1024;
    char* lB0 = (char*)&sB[0][0] + wave * 2048 + lane * 16;
    char* lB1 = lB0 + 1024;

    for (int k0 = 0; k0 < K; k0 += 32) {
        __syncthreads();
        gl_lds16(gA0 + k0, lA0);
        gl_lds16(gA1 + k0, lA1);
        gl_lds16(gB0 + k0, lB0);
        gl_lds16(gB1 + k0, lB1);
        __syncthreads();
        bhalf8 af[4], bfr[4];
        #pragma unroll
        for (int t = 0; t < 4; t++) af[t]  = *(const bhalf8*)&sA[wm * 64 + t * 16 + lrow][quad * 8];
        #pragma unroll
        for (int t = 0; t < 4; t++) bfr[t] = *(const bhalf8*)&sB[wn * 64 + t * 16 + lrow][quad * 8];
        #pragma unroll
        for (int tm = 0; tm < 4; tm++)
            #pragma unroll
            for (int tn = 0; tn < 4; tn++)
                acc[tm][tn] = __builtin_amdgcn_mfma_f32_16x16x32_bf16(af[tm], bfr[tn], acc[tm][tn], 0, 0, 0);
    }

    #pragma unroll
    for (int tm = 0; tm < 4; tm++) {
        #pragma unroll
        for (int tn = 0; tn < 4; tn++) {
            const int col = bx * 128 + wn * 64 + tn * 16 + lrow;
            #pragma unroll
            for (int r = 0; r < 4; r++) {
                const int row = by * 128 + wm * 64 + tm * 16 + quad * 4 + r;
                C[(size_t)row * N + col] = f2b(acc[tm][tn][r]);
            }
        }
    }
}

// -------------------------------------------------------------------------
// Fused: transpose_p (blocks [0,8192)) + compute_sw (blocks [8192,16384)).
// Both read p1; mutually independent.
__global__ __launch_bounds__(256) void tsw_k(const bf16* __restrict__ p1,
                                             bf16* __restrict__ pT,
                                             const void* __restrict__ a_src,
                                             const void* __restrict__ a_tgt,
                                             float* __restrict__ s_src_t,
                                             float* __restrict__ s_tgt_t,
                                             const int* __restrict__ flagp)
{
    __shared__ bf16 tile[32][33];
    const int tid = threadIdx.x;
    int id = blockIdx.x;
    if (id < 8192) {
        // ---- transpose_p: per b, (1024 x 2048) -> (2048 x 1024) ----
        const int bx = id & 63, byy = (id >> 6) & 31, bz = id >> 11;
        const int tx = tid & 31, ty = tid >> 5;
        const int c0 = bx * 32, r0 = byy * 32;
        const bf16* ib = p1 + (size_t)bz * 1024 * 2048;
        bf16* ob = pT + (size_t)bz * 1024 * 2048;
        #pragma unroll
        for (int yy = ty; yy < 32; yy += 8)
            tile[yy][tx] = ib[(size_t)(r0 + yy) * 2048 + c0 + tx];
        __syncthreads();
        #pragma unroll
        for (int yy = ty; yy < 32; yy += 8)
            ob[(size_t)(c0 + yy) * 1024 + r0 + tx] = tile[tx][yy];
        return;
    }
    // ---- compute_sw: wave-autonomous dot over f=256 ----
    id -= 8192;
    const int f32 = *flagp;
    const int bh = id & 31, ny = id >> 5;
    const int b = bh >> 3, h = bh & 7;
    const int wave = tid >> 6, lane = tid & 63;
    const int n = ny * 4 + wave;
    const bf16* pr = p1 + ((size_t)(b * 1024 + n)) * 2048 + h * 256;
    float ss = 0.f, st = 0.f;
    #pragma unroll
    for (int q = 0; q < 4; q++) {
        const int f = q * 64 + lane;
        float pv = b2f(pr[f]);
        ss = fmaf(pv, loadf(a_src, h * 256 + f, f32), ss);
        st = fmaf(pv, loadf(a_tgt, h * 256 + f, f32), st);
    }
    #pragma unroll
    for (int off = 32; off; off >>= 1) {
        ss += __shfl_down(ss, off, 64);
        st += __shfl_down(st, off, 64);
    }
    if (lane == 0) {
        s_src_t[bh * 1024 + n] = ss;
        s_tgt_t[bh * 1024 + n] = st;
    }
}

// -------------------------------------------------------------------------
// Fused layer-1 attention v3 (unchanged R9): 32x256 tile, BK=32, dbuf,
// s_tgt LDS-cached bf16, mask register-prefetched one iteration ahead.
__global__ __launch_bounds__(256) void attn_fused(const float* __restrict__ s_src_t,
                                                  const float* __restrict__ s_tgt_t,
                                                  const void* __restrict__ mask,
                                                  const bf16* __restrict__ pT,
                                                  const bf16* __restrict__ sk,
                                                  const void* __restrict__ bias,
                                                  bf16* __restrict__ x2,
                                                  const int* __restrict__ flag)
{
    __shared__ __align__(16) short sA[2][32][32];    // exp numerators
    __shared__ __align__(16) short sB[2][256][32];   // pT tile (f x k)
    __shared__ short sStgt[1024];                    // s_tgt (bf16)
    __shared__ float sInvl[32];

    const int tid = threadIdx.x;
    const int by = blockIdx.x, bh = blockIdx.y;
    const int b = bh >> 3, h = bh & 7;
    const int f32 = *flag;
    const int wave = tid >> 6, lane = tid & 63;
    const int lrow = lane & 15, quad = lane >> 4;

    #pragma unroll
    for (int q = 0; q < 4; q++)
        sStgt[q * 256 + tid] = f2s(s_tgt_t[bh * 1024 + q * 256 + tid]);

    const int row  = tid >> 3;            // 0..31
    const int col0 = (tid & 7) * 4;       // 0..28
    const float ssr = s_src_t[bh * 1024 + by * 32 + row];
    const size_t mrow0 = ((size_t)(b * 1024 + by * 32 + row)) << 10;

    const bf16* gB = pT + ((size_t)bh << 18) + (size_t)(tid >> 2) * 1024 + (tid & 3) * 8;

    floatx4 acc[2][4];
    #pragma unroll
    for (int i = 0; i < 2; i++)
        #pragma unroll
        for (int j = 0; j < 4; j++)
            acc[i][j] = (floatx4){0.f, 0.f, 0.f, 0.f};

    float lacc = 0.f;

    auto stageB = [&](int k0, int buf) {
        const bf16* g = gB + k0;
        char* l = (char*)&sB[buf][0][0] + tid * 16;
        #pragma unroll
        for (int c = 0; c < 4; c++)
            gl_lds16(g + (size_t)(64 * c) * 1024, l + c * 4096);
    };
    auto genA = [&](int k0, int buf, const float* mv) {
        const short* sp = &sStgt[k0 + col0];
        short4v ev;
        #pragma unroll
        for (int t = 0; t < 4; t++) {
            union { short s; bf16 b; } u; u.s = sp[t];
            float x = ssr + b2f(u.b);
            x = fmaxf(x, 0.2f * x);          // leaky_relu(0.2)
            float e = __expf(x + mv[t]);
            lacc += e;
            ev[t] = f2s(e);
        }
        *(short4v*)&sA[buf][row][col0] = ev;
    };

    float mv[4];
    stageB(0, 0);
    load_mask4(mask, mrow0 + col0, f32, mv);
    __syncthreads();
    genA(0, 0, mv);
    load_mask4(mask, mrow0 + 32 + col0, f32, mv);

    int cur = 0;
    for (int k0 = 0; k0 < 1024; k0 += 32, cur ^= 1) {
        __syncthreads();
        if (k0 + 32 < 1024) {
            const int nxt = cur ^ 1;
            stageB(k0 + 32, nxt);
            genA(k0 + 32, nxt, mv);
            if (k0 + 64 < 1024)
                load_mask4(mask, mrow0 + k0 + 64 + col0, f32, mv);
        }
        bhalf8 af[2], bfr[4];
        #pragma unroll
        for (int mt = 0; mt < 2; mt++)
            af[mt] = *(const bhalf8*)&sA[cur][mt * 16 + lrow][quad * 8];
        #pragma unroll
        for (int nt = 0; nt < 4; nt++)
            bfr[nt] = *(const bhalf8*)&sB[cur][wave * 64 + nt * 16 + lrow][quad * 8];
        #pragma unroll
        for (int mt = 0; mt < 2; mt++)
            #pragma unroll
            for (int nt = 0; nt < 4; nt++)
                acc[mt][nt] = __builtin_amdgcn_mfma_f32_16x16x32_bf16(af[mt], bfr[nt], acc[mt][nt], 0, 0, 0);
    }

    lacc += __shfl_xor(lacc, 1, 64);
    lacc += __shfl_xor(lacc, 2, 64);
    lacc += __shfl_xor(lacc, 4, 64);
    if ((tid & 7) == 0) sInvl[row] = 1.0f / lacc;
    __syncthreads();

    #pragma unroll
    for (int mt = 0; mt < 2; mt++) {
        #pragma unroll
        for (int r = 0; r < 4; r++) {
            const int rl = mt * 16 + quad * 4 + r;
            const int rg = by * 32 + rl;
            const float il = sInvl[rl];
            #pragma unroll
            for (int nt = 0; nt < 4; nt++) {
                const int col = wave * 64 + nt * 16 + lrow;
                const int hf = h * 256 + col;
                const size_t idx = ((size_t)(b * 1024 + rg)) * 2048 + hf;
                float v = acc[mt][nt][r] * il + b2f(sk[idx]) + loadf(bias, hf, f32);
                v = (v > 0.f) ? v : expm1f(v);     // ELU
                x2[idx] = f2b(v);
            }
        }
    }
}

// -------------------------------------------------------------------------
// Layer-2 scores (unchanged R9).
__global__ __launch_bounds__(256) void score2_k(const bf16* __restrict__ x2,
                                                const float* __restrict__ Wa,
                                                float* __restrict__ s_src_t,
                                                float* __restrict__ s_tgt_t)
{
    const int bid = blockIdx.x;
    const int b = bid >> 10, n = bid & 1023;
    const int wave = threadIdx.x >> 6, lane = threadIdx.x & 63;
    const bf16* xr = x2 + (size_t)bid * 2048;
    float xv[32];
    #pragma unroll
    for (int q = 0; q < 32; q++) xv[q] = b2f(xr[q * 64 + lane]);
    #pragma unroll
    for (int c = 0; c < 4; c++) {
        const int hh = c * 4 + wave;
        const float* wr = Wa + hh * 2048;
        float acc = 0.f;
        #pragma unroll
        for (int q = 0; q < 32; q++) acc = fmaf(xv[q], wr[q * 64 + lane], acc);
        #pragma unroll
        for (int off = 32; off; off >>= 1) acc += __shfl_down(acc, off, 64);
        if (lane == 0) {
            if (hh < 8) s_src_t[(b * 8 + hh) * 1024 + n] = acc;
            else        s_tgt_t[(b * 8 + hh - 8) * 1024 + n] = acc;
        }
    }
}

// -------------------------------------------------------------------------
// Fused layer-2 denominators + weighted column sums. Grid (32 bh, 16 iz of
// 64 rows). Same total exp count as lpass+colsum2, one dispatch, no invl.
__global__ __launch_bounds__(256) void colsoft_k(const float* __restrict__ s_src_t,
                                                 const float* __restrict__ s_tgt_t,
                                                 const void* __restrict__ mask,
                                                 float* __restrict__ c,
                                                 const int* __restrict__ flagp)
{
    __shared__ float sS[64];
    __shared__ float sIl[64];
    const int f32 = *flagp;
    const int bh = blockIdx.x, iz = blockIdx.y, b = bh >> 3;
    const int tid = threadIdx.x;
    const int i0 = iz * 64;
    if (tid < 64) sS[tid] = s_src_t[bh * 1024 + i0 + tid];
    __syncthreads();

    // ---- pass 1: row denominators (4 threads/row, 256 j each) ----
    {
        const int row = tid >> 2, c4 = tid & 3;
        const float ssr = sS[row];
        const size_t mrow = ((size_t)(b * 1024 + i0 + row)) << 10;
        float l = 0.f;
        #pragma unroll 4
        for (int q = 0; q < 64; q++) {
            const int j = c4 * 256 + q * 4;
            float mv[4];
            load_mask4(mask, mrow + j, f32, mv);
            float4 s4 = *(const float4*)(s_tgt_t + bh * 1024 + j);
            float sv[4] = {s4.x, s4.y, s4.z, s4.w};
            #pragma unroll
            for (int t = 0; t < 4; t++) {
                float x = ssr + sv[t];
                x = fmaxf(x, 0.2f * x);
                l += __expf(x + mv[t]);
            }
        }
        l += __shfl_xor(l, 1, 64);
        l += __shfl_xor(l, 2, 64);
        if ((tid & 3) == 0) sIl[row] = 1.0f / l;
    }
    __syncthreads();

    // ---- pass 2: column partial sums (thread = 4 cols, loop 64 rows) ----
    const int j0 = tid * 4;
    float4 s4 = *(const float4*)(s_tgt_t + bh * 1024 + j0);
    float sv[4] = {s4.x, s4.y, s4.z, s4.w};
    float a[4] = {0.f, 0.f, 0.f, 0.f};
    #pragma unroll 4
    for (int r = 0; r < 64; r++) {
        const float sr = sS[r], il = sIl[r];
        float mv[4];
        load_mask4(mask, (((size_t)(b * 1024 + i0 + r)) << 10) + j0, f32, mv);
        #pragma unroll
        for (int t = 0; t < 4; t++) {
            float x = sr + sv[t];
            x = fmaxf(x, 0.2f * x);
            a[t] = fmaf(il, __expf(x + mv[t]), a[t]);
        }
    }
    #pragma unroll
    for (int t = 0; t < 4; t++)
        atomicAdd(&c[bh * 1024 + j0 + t], a[t]);
}

// -------------------------------------------------------------------------
// y[bh][k] += sum_{j in chunk} c[bh,j]*x2[b,j,k]; xbar += rowsum (unchanged R9)
__global__ __launch_bounds__(256) void yx_k(const bf16* __restrict__ x2,
                                            const float* __restrict__ c,
                                            float* __restrict__ y,
                                            float* __restrict__ xbar)
{
    __shared__ float sC[8][128];
    const int b = blockIdx.x, kt = blockIdx.y, jc = blockIdx.z;
    const int t = threadIdx.x;
    const int k = kt * 256 + t;
    const int j0 = jc * 128;
    for (int idx = t; idx < 8 * 128; idx += 256) {
        const int h = idx >> 7, jj = idx & 127;
        sC[h][jj] = c[(b * 8 + h) * 1024 + j0 + jj];
    }
    __syncthreads();
    float acc[8] = {0.f, 0.f, 0.f, 0.f, 0.f, 0.f, 0.f, 0.f};
    float ax = 0.f;
    for (int jj = 0; jj < 128; jj++) {
        const float xv = b2f(x2[((size_t)(b * 1024 + j0 + jj)) * 2048 + k]);
        ax += xv;
        #pragma unroll
        for (int h = 0; h < 8; h++) acc[h] = fmaf(sC[h][jj], xv, acc[h]);
    }
    #pragma unroll
    for (int h = 0; h < 8; h++)
        atomicAdd(&y[(b * 8 + h) * 2048 + k], acc[h]);
    atomicAdd(&xbar[b * 2048 + k], ax);
}

// -------------------------------------------------------------------------
// Fused gamat (blocks [0,256)) + skipvec (blocks [256,512)). R9 bodies.
__global__ __launch_bounds__(256) void gs_k(const void* __restrict__ W2,
                                            const void* __restrict__ skip2,
                                            const float* __restrict__ y,
                                            const float* __restrict__ xbar,
                                            float* __restrict__ gA,
                                            float* __restrict__ gS,
                                            const int* __restrict__ flagp)
{
    __shared__ float sY[256];
    const int f32 = *flagp;
    int id = blockIdx.x;
    if (id < 256) {
        // gamat: bh = id & 31, kc = id >> 5
        const int bh = id & 31, kc = id >> 5;
        const int h = bh & 7, f = threadIdx.x;
        const int k0 = kc * 256;
        sY[threadIdx.x] = y[bh * 2048 + k0 + threadIdx.x];
        __syncthreads();
        float acc = 0.f;
        #pragma unroll 4
        for (int kk = 0; kk < 256; kk++)
            acc = fmaf(sY[kk], loadf(W2, (size_t)(k0 + kk) * 2048 + h * 256 + f, f32), acc);
        atomicAdd(&gA[bh * 256 + f], acc);
    } else {
        // skipvec: idx -> b(4), hft(8), kc(8)
        const int idx = id - 256;
        const int b = idx & 3, hft = (idx >> 2) & 7, kc = idx >> 5;
        const int hf = hft * 256 + threadIdx.x;
        float acc = 0.f;
        #pragma unroll 4
        for (int kk = 0; kk < 256; kk++) {
            const int k = kc * 256 + kk;
            acc = fmaf(xbar[b * 2048 + k], loadf(skip2, (size_t)k * 2048 + hf, f32), acc);
        }
        atomicAdd(&gS[b * 2048 + hf], acc);
    }
}

// -------------------------------------------------------------------------
// g[b,f] = (sum_h gA + sum_h gS)/(8*1024) + b2[f]; out = g@Wc + bc (unchanged)
__global__ __launch_bounds__(256) void classify2_k(const float* __restrict__ gA,
                                                   const float* __restrict__ gS,
                                                   const void* __restrict__ b2,
                                                   const void* __restrict__ Wc,
                                                   const void* __restrict__ bc,
                                                   void* __restrict__ out,
                                                   const int* __restrict__ flag)
{
    __shared__ float gv[256];
    const int f32 = *flag;
    const int b = blockIdx.x, f = threadIdx.x;
    float s = 0.f;
    #pragma unroll
    for (int h = 0; h < 8; h++)
        s += gA[(b * 8 + h) * 256 + f] + gS[b * 2048 + h * 256 + f];
    gv[f] = s * (1.0f / 8192.0f) + loadf(b2, f, f32);
    __syncthreads();
    if (f < 10) {
        float acc = loadf(bc, f, f32);
        for (int k = 0; k < 256; k++)
            acc = fmaf(gv[k], loadf(Wc, k * 10 + f, f32), acc);
        if (f32) ((float*)out)[b * 10 + f] = acc;
        else     ((bf16*)out)[b * 10 + f] = f2b(acc);
    }
}

// -------------------------------------------------------------------------
extern "C" void kernel_launch(void* const* d_in, const int* in_sizes, int n_in,
                              void* d_out, int out_size, void* d_ws, size_t ws_size,
                              hipStream_t stream)
{
    (void)in_sizes; (void)n_in; (void)out_size; (void)ws_size;
    const void* feat   = d_in[0];
    const void* mask   = d_in[2];
    const void* W1     = d_in[3];
    const void* a_src1 = d_in[4];
    const void* a_tgt1 = d_in[5];
    const void* skip1  = d_in[6];
    const void* b1     = d_in[7];
    const void* W2     = d_in[8];
    const void* a_src2 = d_in[9];
    const void* a_tgt2 = d_in[10];
    const void* skip2  = d_in[11];
    const void* b2v    = d_in[12];
    const void* Wc     = d_in[13];
    const void* bc     = d_in[14];

    char* ws = (char*)d_ws;
    size_t off = 0;
    auto alloc = [&](size_t bytes) -> void* {
        void* p = ws + off;
        off += (bytes + 255) & ~(size_t)255;
        return p;
    };
    int*   flag = (int*)alloc(256);
    bf16*  featc= (bf16*)alloc(4096ull * 256 * 2);
    bf16*  W1t  = (bf16*)alloc(2048ull * 256 * 2);
    bf16*  S1t  = (bf16*)alloc(2048ull * 256 * 2);
    bf16*  p1   = (bf16*)alloc(4096ull * 2048 * 2);
    bf16*  sk1  = (bf16*)alloc(4096ull * 2048 * 2);
    bf16*  x2   = (bf16*)alloc(4096ull * 2048 * 2);
    bf16*  pT   = (bf16*)alloc(4096ull * 2048 * 2);
    float* ss   = (float*)alloc(32ull * 1024 * 4);
    float* st   = (float*)alloc(32ull * 1024 * 4);
    float* Wa   = (float*)alloc(16ull * 2048 * 4);
    // cbuf, gA, gS, xbar, y contiguous: zeroed in prep_k
    float* cbuf = (float*)alloc(32ull * 1024 * 4);     // 32768 floats
    float* gA   = (float*)alloc(32ull * 256 * 4);      // 8192
    float* gS   = (float*)alloc(4ull * 2048 * 4);      // 8192
    float* xbar = (float*)alloc(4ull * 2048 * 4);      // 8192
    float* y    = (float*)alloc(32ull * 2048 * 4);     // 65536
    const int nzero = 32768 + 3 * 8192 + 65536;        // 122880

    // 1. fused prep (detect + cvt + zero + transposes + wproj)
    prep_k<<<5728, 256, 0, stream>>>(feat, featc, cbuf, nzero, W1, W1t,
                                     skip1, S1t, W2, a_src2, a_tgt2, Wa, flag);
    // 2. layer-1 paired GEMM
    gemm_bt2<<<dim3(16, 32, 2), 256, 0, stream>>>(featc, W1t, S1t, p1, sk1, 4096, 2048, 256);
    // 3. fused transpose_p + compute_sw
    tsw_k<<<16384, 256, 0, stream>>>(p1, pT, a_src1, a_tgt1, ss, st, flag);
    // 4. fused layer-1 attention
    attn_fused<<<dim3(32, 32), 256, 0, stream>>>(ss, st, mask, pT, sk1, b1, x2, flag);
    // 5. layer-2 scores
    score2_k<<<4096, 256, 0, stream>>>(x2, Wa, ss, st);
    // 6. fused softmax denominators + column sums
    colsoft_k<<<dim3(32, 16), 256, 0, stream>>>(ss, st, mask, cbuf, flag);
    // 7. weighted + plain row aggregation of x2
    yx_k<<<dim3(4, 8, 8), 256, 0, stream>>>(x2, cbuf, y, xbar);
    // 8. fused gamat + skipvec
    gs_k<<<512, 256, 0, stream>>>(W2, skip2, y, xbar, gA, gS, flag);
    // 9. classify
    classify2_k<<<4, 256, 0, stream>>>(gA, gS, b2v, Wc, bc, d_out, flag);
}

// Round 11
// 400.019 us; speedup vs baseline: 1.2606x; 1.0366x over previous
//
#include <hip/hip_runtime.h>
#include <hip/hip_bf16.h>
#include <stdint.h>
#include <stddef.h>

typedef __hip_bfloat16 bf16;
typedef __attribute__((ext_vector_type(8))) short bhalf8;
typedef __attribute__((ext_vector_type(4))) short short4v;
typedef __attribute__((ext_vector_type(4))) float floatx4;

static __device__ __forceinline__ float b2f(bf16 v) { return __bfloat162float(v); }
static __device__ __forceinline__ bf16  f2b(float v) { return __float2bfloat16(v); }
static __device__ __forceinline__ short f2s(float v) {
    union { bf16 b; short s; } u; u.b = __float2bfloat16(v); return u.s;
}
static __device__ __forceinline__ float s2f(short v) {
    union { short s; bf16 b; } u; u.s = v; return b2f(u.b);
}

// dtype-agnostic scalar load: flag==1 -> fp32 data, flag==0 -> bf16 data
static __device__ __forceinline__ float loadf(const void* p, size_t i, int f32) {
    return f32 ? ((const float*)p)[i] : b2f(((const bf16*)p)[i]);
}

// async global->LDS, 16B per lane. LDS dest must be wave-uniform base + lane*16.
static __device__ __forceinline__ void gl_lds16(const void* g, void* l) {
    __builtin_amdgcn_global_load_lds(
        (const __attribute__((address_space(1))) void*)g,
        (__attribute__((address_space(3))) void*)l, 16, 0, 0);
}

// load 4 consecutive mask values at 4-aligned index
static __device__ __forceinline__ void load_mask4(const void* mask, size_t idx,
                                                  int f32, float* mv) {
    if (f32) {
        float4 v = *(const float4*)((const float*)mask + idx);
        mv[0] = v.x; mv[1] = v.y; mv[2] = v.z; mv[3] = v.w;
    } else {
        const bf16* p = (const bf16*)mask + idx;
        #pragma unroll
        for (int t = 0; t < 4; t++) mv[t] = b2f(p[t]);
    }
}

// -------------------------------------------------------------------------
// Fused prep: inline dtype-detect + [cvt feat | zero accumulators |
// transpose W1 | transpose skip1 | wproj2 (Wa2 bf16) | wproj1 (Wa1 bf16)].
// Segments: [0,4096) cvt, +480 zero, +512 T(W1), +512 T(skip1),
// +128 wproj2, +16 wproj1.  Total 5744 blocks.
__global__ __launch_bounds__(256) void prep_k(const void* __restrict__ feat,
                                              bf16* __restrict__ featc,
                                              float* __restrict__ zbase, int nzero,
                                              const void* __restrict__ W1,
                                              bf16* __restrict__ W1t,
                                              const void* __restrict__ skip1,
                                              bf16* __restrict__ S1t,
                                              const void* __restrict__ W2,
                                              const void* __restrict__ a_src1,
                                              const void* __restrict__ a_tgt1,
                                              const void* __restrict__ a_src2,
                                              const void* __restrict__ a_tgt2,
                                              bf16* __restrict__ Wa1b,
                                              bf16* __restrict__ Wa2b,
                                              int* __restrict__ flagp)
{
    __shared__ int sflag;
    __shared__ bf16 tile[32][33];
    const int tid = threadIdx.x;

    // inline dtype detection from W1 raw bits (values ~ N(0,0.05))
    if (tid < 64) {
        const unsigned short* s = (const unsigned short*)W1;
        int bad = 0;
        #pragma unroll
        for (int i = 0; i < 4; i++) {
            int e = (s[tid * 4 + i] >> 7) & 0xFF;
            if (e > 0x85 || (e != 0 && e < 0x60)) bad++;
        }
        bad += __shfl_xor(bad, 1, 64);
        bad += __shfl_xor(bad, 2, 64);
        bad += __shfl_xor(bad, 4, 64);
        bad += __shfl_xor(bad, 8, 64);
        bad += __shfl_xor(bad, 16, 64);
        bad += __shfl_xor(bad, 32, 64);
        if (tid == 0) sflag = (bad > 16) ? 1 : 0;
    }
    __syncthreads();
    const int f32 = sflag;

    int id = blockIdx.x;
    if (id == 0 && tid == 0) *flagp = f32;     // publish for later dispatches

    if (id < 4096) {                           // ---- cvt feat -> bf16 ----
        const int i = id * 256 + tid;
        featc[i] = f32 ? f2b(((const float*)feat)[i]) : ((const bf16*)feat)[i];
        return;
    }
    id -= 4096;
    if (id < 480) {                            // ---- zero accumulators ----
        const int i = id * 256 + tid;
        if (i < nzero) zbase[i] = 0.f;
        return;
    }
    id -= 480;
    if (id < 1024) {                           // ---- transposes (256x2048) ----
        const void* in = (id < 512) ? W1 : skip1;
        bf16* out = (id < 512) ? W1t : S1t;
        const int t = id & 511;
        const int bx = t & 63, byy = t >> 6;
        const int tx = tid & 31, ty = tid >> 5;
        const int c0 = bx * 32, r0 = byy * 32;
        #pragma unroll
        for (int yy = ty; yy < 32; yy += 8)
            tile[yy][tx] = f2b(loadf(in, (size_t)(r0 + yy) * 2048 + c0 + tx, f32));
        __syncthreads();
        #pragma unroll
        for (int yy = ty; yy < 32; yy += 8)
            out[(size_t)(c0 + yy) * 256 + r0 + tx] = tile[tx][yy];
        return;
    }
    id -= 1024;
    if (id < 128) {
        // ---- wproj2: Wa2b[hh*2048+k] = sum_f W2[k,h*256+f]*a2[h][f] ----
        const int wave = tid >> 6, lane = tid & 63;
        const int base = id * 256;
        const int hh = base >> 11, h = hh & 7;
        const void* a = (hh < 8) ? a_src2 : a_tgt2;
        float av[4];
        #pragma unroll
        for (int i = 0; i < 4; i++) av[i] = loadf(a, h * 256 + lane * 4 + i, f32);
        for (int o = 0; o < 64; o++) {
            const int idx = base + wave * 64 + o;
            const int k = idx & 2047;
            float acc = 0.f;
            #pragma unroll
            for (int i = 0; i < 4; i++)
                acc = fmaf(loadf(W2, (size_t)k * 2048 + h * 256 + lane * 4 + i, f32),
                           av[i], acc);
            #pragma unroll
            for (int off2 = 32; off2; off2 >>= 1) acc += __shfl_down(acc, off2, 64);
            if (lane == 0) Wa2b[idx] = f2b(acc);
        }
        return;
    }
    id -= 128;
    // ---- wproj1: Wa1b[hh*256+k] = sum_f W1[k,h*256+f]*a1[h][f], k<256 ----
    {
        const int wave = tid >> 6, lane = tid & 63;
        const int base = id * 256;                    // id 0..15
        const int hh = base >> 8, h = hh & 7;         // hh = id
        const void* a = (hh < 8) ? a_src1 : a_tgt1;
        float av[4];
        #pragma unroll
        for (int i = 0; i < 4; i++) av[i] = loadf(a, h * 256 + lane * 4 + i, f32);
        for (int o = 0; o < 64; o++) {
            const int idx = base + wave * 64 + o;
            const int k = idx & 255;
            float acc = 0.f;
            #pragma unroll
            for (int i = 0; i < 4; i++)
                acc = fmaf(loadf(W1, (size_t)k * 2048 + h * 256 + lane * 4 + i, f32),
                           av[i], acc);
            #pragma unroll
            for (int off2 = 32; off2; off2 >>= 1) acc += __shfl_down(acc, off2, 64);
            if (lane == 0) Wa1b[idx] = f2b(acc);
        }
    }
}

// -------------------------------------------------------------------------
// Dual GEMM, K=256, m97 structure, grid (32,16,2):
//  z=0: pT  = W1t(2048x256) @ featc^T  -> written in per-(b,h) [f][n] layout
//  z=1: sk1 = featc(4096x256) @ S1t^T  -> row-major (node, 2048)
__global__ __launch_bounds__(256) void gemm_dual(const bf16* __restrict__ featc,
                                                 const bf16* __restrict__ W1t,
                                                 const bf16* __restrict__ S1t,
                                                 bf16* __restrict__ pT,
                                                 bf16* __restrict__ sk1)
{
    __shared__ __align__(16) short sA[128][32];
    __shared__ __align__(16) short sB[128][32];
    const int tid = threadIdx.x;
    const int z = blockIdx.z;
    const bf16* A  = z ? featc : W1t;
    const bf16* Bt = z ? S1t   : featc;
    const int mbase = (z ? blockIdx.x : blockIdx.y) * 128;
    const int nbase = (z ? blockIdx.y : blockIdx.x) * 128;
    const int wave = tid >> 6, lane = tid & 63;
    const int wm = wave >> 1, wn = wave & 1;
    const int lrow = lane & 15, quad = lane >> 4;

    floatx4 acc[4][4];
    #pragma unroll
    for (int i = 0; i < 4; i++)
        #pragma unroll
        for (int j = 0; j < 4; j++)
            acc[i][j] = (floatx4){0.f, 0.f, 0.f, 0.f};

    const int srow = wave * 32 + (lane >> 2);
    const int scol = (lane & 3) * 8;
    const bf16* gA0 = A  + (size_t)(mbase + srow) * 256 + scol;
    const bf16* gA1 = gA0 + (size_t)16 * 256;
    const bf16* gB0 = Bt + (size_t)(nbase + srow) * 256 + scol;
    const bf16* gB1 = gB0 + (size_t)16 * 256;
    char* lA0 = (char*)&sA[0][0] + wave * 2048 + lane * 16;
    char* lA1 = lA0 + 1024;
    char* lB0 = (char*)&sB[0][0] + wave * 2048 + lane * 16;
    char* lB1 = lB0 + 1024;

    for (int k0 = 0; k0 < 256; k0 += 32) {
        __syncthreads();
        gl_lds16(gA0 + k0, lA0);
        gl_lds16(gA1 + k0, lA1);
        gl_lds16(gB0 + k0, lB0);
        gl_lds16(gB1 + k0, lB1);
        __syncthreads();
        bhalf8 af[4], bfr[4];
        #pragma unroll
        for (int t = 0; t < 4; t++) af[t]  = *(const bhalf8*)&sA[wm * 64 + t * 16 + lrow][quad * 8];
        #pragma unroll
        for (int t = 0; t < 4; t++) bfr[t] = *(const bhalf8*)&sB[wn * 64 + t * 16 + lrow][quad * 8];
        #pragma unroll
        for (int tm = 0; tm < 4; tm++)
            #pragma unroll
            for (int tn = 0; tn < 4; tn++)
                acc[tm][tn] = __builtin_amdgcn_mfma_f32_16x16x32_bf16(af[tm], bfr[tn], acc[tm][tn], 0, 0, 0);
    }

    #pragma unroll
    for (int tm = 0; tm < 4; tm++) {
        #pragma unroll
        for (int tn = 0; tn < 4; tn++) {
            const int col = nbase + wn * 64 + tn * 16 + lrow;
            #pragma unroll
            for (int r = 0; r < 4; r++) {
                const int row = mbase + wm * 64 + tm * 16 + quad * 4 + r;
                if (z) {
                    sk1[(size_t)row * 2048 + col] = f2b(acc[tm][tn][r]);
                } else {
                    // row = h*256+f (M=2048), col = b*1024+n (N=4096)
                    const size_t idx = ((size_t)((col >> 10) * 8 + (row >> 8)) << 18)
                                     + (size_t)(row & 255) * 1024 + (col & 1023);
                    pT[idx] = f2b(acc[tm][tn][r]);
                }
            }
        }
    }
}

// -------------------------------------------------------------------------
// Scores: ss/st[bh][n] = sum_k X[n,k] * Wab[hh][k]  (bf16 X, bf16 Wa).
// Wave per node (grid 1024 x 4 waves), lane-contiguous bhalf8 loads.
template <int K>
__global__ __launch_bounds__(256) void score_k(const bf16* __restrict__ X,
                                               const bf16* __restrict__ Wab,
                                               float* __restrict__ ss,
                                               float* __restrict__ st)
{
    constexpr int VPL = K / 64;                   // values per lane
    const int wave = threadIdx.x >> 6, lane = threadIdx.x & 63;
    const int n = blockIdx.x * 4 + wave;          // 0..4095
    const int b = n >> 10, nn = n & 1023;

    const bf16* xr = X + (size_t)n * K + lane * VPL;
    float xv[VPL];
    if (VPL == 4) {
        short4v v = *(const short4v*)xr;
        #pragma unroll
        for (int t = 0; t < 4; t++) xv[t] = s2f(v[t]);
    } else {
        #pragma unroll
        for (int c = 0; c < VPL / 8; c++) {
            bhalf8 v = *(const bhalf8*)(xr + c * 8);
            #pragma unroll
            for (int t = 0; t < 8; t++) xv[c * 8 + t] = s2f(v[t]);
        }
    }

    #pragma unroll
    for (int hh = 0; hh < 16; hh++) {
        const bf16* wr = Wab + (size_t)hh * K + lane * VPL;
        float acc = 0.f;
        if (VPL == 4) {
            short4v v = *(const short4v*)wr;
            #pragma unroll
            for (int t = 0; t < 4; t++) acc = fmaf(xv[t], s2f(v[t]), acc);
        } else {
            #pragma unroll
            for (int c = 0; c < VPL / 8; c++) {
                bhalf8 v = *(const bhalf8*)(wr + c * 8);
                #pragma unroll
                for (int t = 0; t < 8; t++) acc = fmaf(xv[c * 8 + t], s2f(v[t]), acc);
            }
        }
        #pragma unroll
        for (int off = 32; off; off >>= 1) acc += __shfl_down(acc, off, 64);
        if (lane == 0) {
            const int h = hh & 7;
            if (hh < 8) ss[(b * 8 + h) * 1024 + nn] = acc;
            else        st[(b * 8 + h) * 1024 + nn] = acc;
        }
    }
}

// -------------------------------------------------------------------------
// Fused layer-1 attention v3 (unchanged R9/R10).
__global__ __launch_bounds__(256) void attn_fused(const float* __restrict__ s_src_t,
                                                  const float* __restrict__ s_tgt_t,
                                                  const void* __restrict__ mask,
                                                  const bf16* __restrict__ pT,
                                                  const bf16* __restrict__ sk,
                                                  const void* __restrict__ bias,
                                                  bf16* __restrict__ x2,
                                                  const int* __restrict__ flag)
{
    __shared__ __align__(16) short sA[2][32][32];    // exp numerators
    __shared__ __align__(16) short sB[2][256][32];   // pT tile (f x k)
    __shared__ short sStgt[1024];                    // s_tgt (bf16)
    __shared__ float sInvl[32];

    const int tid = threadIdx.x;
    const int by = blockIdx.x, bh = blockIdx.y;
    const int b = bh >> 3, h = bh & 7;
    const int f32 = *flag;
    const int wave = tid >> 6, lane = tid & 63;
    const int lrow = lane & 15, quad = lane >> 4;

    #pragma unroll
    for (int q = 0; q < 4; q++)
        sStgt[q * 256 + tid] = f2s(s_tgt_t[bh * 1024 + q * 256 + tid]);

    const int row  = tid >> 3;            // 0..31
    const int col0 = (tid & 7) * 4;       // 0..28
    const float ssr = s_src_t[bh * 1024 + by * 32 + row];
    const size_t mrow0 = ((size_t)(b * 1024 + by * 32 + row)) << 10;

    const bf16* gB = pT + ((size_t)bh << 18) + (size_t)(tid >> 2) * 1024 + (tid & 3) * 8;

    floatx4 acc[2][4];
    #pragma unroll
    for (int i = 0; i < 2; i++)
        #pragma unroll
        for (int j = 0; j < 4; j++)
            acc[i][j] = (floatx4){0.f, 0.f, 0.f, 0.f};

    float lacc = 0.f;

    auto stageB = [&](int k0, int buf) {
        const bf16* g = gB + k0;
        char* l = (char*)&sB[buf][0][0] + tid * 16;
        #pragma unroll
        for (int c = 0; c < 4; c++)
            gl_lds16(g + (size_t)(64 * c) * 1024, l + c * 4096);
    };
    auto genA = [&](int k0, int buf, const float* mv) {
        const short* sp = &sStgt[k0 + col0];
        short4v ev;
        #pragma unroll
        for (int t = 0; t < 4; t++) {
            float x = ssr + s2f(sp[t]);
            x = fmaxf(x, 0.2f * x);          // leaky_relu(0.2)
            float e = __expf(x + mv[t]);
            lacc += e;
            ev[t] = f2s(e);
        }
        *(short4v*)&sA[buf][row][col0] = ev;
    };

    float mv[4];
    stageB(0, 0);
    load_mask4(mask, mrow0 + col0, f32, mv);
    __syncthreads();
    genA(0, 0, mv);
    load_mask4(mask, mrow0 + 32 + col0, f32, mv);

    int cur = 0;
    for (int k0 = 0; k0 < 1024; k0 += 32, cur ^= 1) {
        __syncthreads();
        if (k0 + 32 < 1024) {
            const int nxt = cur ^ 1;
            stageB(k0 + 32, nxt);
            genA(k0 + 32, nxt, mv);
            if (k0 + 64 < 1024)
                load_mask4(mask, mrow0 + k0 + 64 + col0, f32, mv);
        }
        bhalf8 af[2], bfr[4];
        #pragma unroll
        for (int mt = 0; mt < 2; mt++)
            af[mt] = *(const bhalf8*)&sA[cur][mt * 16 + lrow][quad * 8];
        #pragma unroll
        for (int nt = 0; nt < 4; nt++)
            bfr[nt] = *(const bhalf8*)&sB[cur][wave * 64 + nt * 16 + lrow][quad * 8];
        #pragma unroll
        for (int mt = 0; mt < 2; mt++)
            #pragma unroll
            for (int nt = 0; nt < 4; nt++)
                acc[mt][nt] = __builtin_amdgcn_mfma_f32_16x16x32_bf16(af[mt], bfr[nt], acc[mt][nt], 0, 0, 0);
    }

    lacc += __shfl_xor(lacc, 1, 64);
    lacc += __shfl_xor(lacc, 2, 64);
    lacc += __shfl_xor(lacc, 4, 64);
    if ((tid & 7) == 0) sInvl[row] = 1.0f / lacc;
    __syncthreads();

    #pragma unroll
    for (int mt = 0; mt < 2; mt++) {
        #pragma unroll
        for (int r = 0; r < 4; r++) {
            const int rl = mt * 16 + quad * 4 + r;
            const int rg = by * 32 + rl;
            const float il = sInvl[rl];
            #pragma unroll
            for (int nt = 0; nt < 4; nt++) {
                const int col = wave * 64 + nt * 16 + lrow;
                const int hf = h * 256 + col;
                const size_t idx = ((size_t)(b * 1024 + rg)) * 2048 + hf;
                float v = acc[mt][nt][r] * il + b2f(sk[idx]) + loadf(bias, hf, f32);
                v = (v > 0.f) ? v : expm1f(v);     // ELU
                x2[idx] = f2b(v);
            }
        }
    }
}

// -------------------------------------------------------------------------
// Fused layer-2 denominators + weighted column sums (unchanged R10).
__global__ __launch_bounds__(256) void colsoft_k(const float* __restrict__ s_src_t,
                                                 const float* __restrict__ s_tgt_t,
                                                 const void* __restrict__ mask,
                                                 float* __restrict__ c,
                                                 const int* __restrict__ flagp)
{
    __shared__ float sS[64];
    __shared__ float sIl[64];
    const int f32 = *flagp;
    const int bh = blockIdx.x, iz = blockIdx.y, b = bh >> 3;
    const int tid = threadIdx.x;
    const int i0 = iz * 64;
    if (tid < 64) sS[tid] = s_src_t[bh * 1024 + i0 + tid];
    __syncthreads();

    {
        const int row = tid >> 2, c4 = tid & 3;
        const float ssr = sS[row];
        const size_t mrow = ((size_t)(b * 1024 + i0 + row)) << 10;
        float l = 0.f;
        #pragma unroll 4
        for (int q = 0; q < 64; q++) {
            const int j = c4 * 256 + q * 4;
            float mv[4];
            load_mask4(mask, mrow + j, f32, mv);
            float4 s4 = *(const float4*)(s_tgt_t + bh * 1024 + j);
            float sv[4] = {s4.x, s4.y, s4.z, s4.w};
            #pragma unroll
            for (int t = 0; t < 4; t++) {
                float x = ssr + sv[t];
                x = fmaxf(x, 0.2f * x);
                l += __expf(x + mv[t]);
            }
        }
        l += __shfl_xor(l, 1, 64);
        l += __shfl_xor(l, 2, 64);
        if ((tid & 3) == 0) sIl[row] = 1.0f / l;
    }
    __syncthreads();

    const int j0 = tid * 4;
    float4 s4 = *(const float4*)(s_tgt_t + bh * 1024 + j0);
    float sv[4] = {s4.x, s4.y, s4.z, s4.w};
    float a[4] = {0.f, 0.f, 0.f, 0.f};
    #pragma unroll 4
    for (int r = 0; r < 64; r++) {
        const float sr = sS[r], il = sIl[r];
        float mv[4];
        load_mask4(mask, (((size_t)(b * 1024 + i0 + r)) << 10) + j0, f32, mv);
        #pragma unroll
        for (int t = 0; t < 4; t++) {
            float x = sr + sv[t];
            x = fmaxf(x, 0.2f * x);
            a[t] = fmaf(il, __expf(x + mv[t]), a[t]);
        }
    }
    #pragma unroll
    for (int t = 0; t < 4; t++)
        atomicAdd(&c[bh * 1024 + j0 + t], a[t]);
}

// -------------------------------------------------------------------------
// y[bh][k] += sum_{j in chunk} c[bh,j]*x2[b,j,k]; xbar += rowsum (unchanged)
__global__ __launch_bounds__(256) void yx_k(const bf16* __restrict__ x2,
                                            const float* __restrict__ c,
                                            float* __restrict__ y,
                                            float* __restrict__ xbar)
{
    __shared__ float sC[8][128];
    const int b = blockIdx.x, kt = blockIdx.y, jc = blockIdx.z;
    const int t = threadIdx.x;
    const int k = kt * 256 + t;
    const int j0 = jc * 128;
    for (int idx = t; idx < 8 * 128; idx += 256) {
        const int h = idx >> 7, jj = idx & 127;
        sC[h][jj] = c[(b * 8 + h) * 1024 + j0 + jj];
    }
    __syncthreads();
    float acc[8] = {0.f, 0.f, 0.f, 0.f, 0.f, 0.f, 0.f, 0.f};
    float ax = 0.f;
    for (int jj = 0; jj < 128; jj++) {
        const float xv = b2f(x2[((size_t)(b * 1024 + j0 + jj)) * 2048 + k]);
        ax += xv;
        #pragma unroll
        for (int h = 0; h < 8; h++) acc[h] = fmaf(sC[h][jj], xv, acc[h]);
    }
    #pragma unroll
    for (int h = 0; h < 8; h++)
        atomicAdd(&y[(b * 8 + h) * 2048 + k], acc[h]);
    atomicAdd(&xbar[b * 2048 + k], ax);
}

// -------------------------------------------------------------------------
// Fused gamat (blocks [0,256)) + skipvec (blocks [256,512)). (unchanged)
__global__ __launch_bounds__(256) void gs_k(const void* __restrict__ W2,
                                            const void* __restrict__ skip2,
                                            const float* __restrict__ y,
                                            const float* __restrict__ xbar,
                                            float* __restrict__ gA,
                                            float* __restrict__ gS,
                                            const int* __restrict__ flagp)
{
    __shared__ float sY[256];
    const int f32 = *flagp;
    int id = blockIdx.x;
    if (id < 256) {
        const int bh = id & 31, kc = id >> 5;
        const int h = bh & 7, f = threadIdx.x;
        const int k0 = kc * 256;
        sY[threadIdx.x] = y[bh * 2048 + k0 + threadIdx.x];
        __syncthreads();
        float acc = 0.f;
        #pragma unroll 4
        for (int kk = 0; kk < 256; kk++)
            acc = fmaf(sY[kk], loadf(W2, (size_t)(k0 + kk) * 2048 + h * 256 + f, f32), acc);
        atomicAdd(&gA[bh * 256 + f], acc);
    } else {
        const int idx = id - 256;
        const int b = idx & 3, hft = (idx >> 2) & 7, kc = idx >> 5;
        const int hf = hft * 256 + threadIdx.x;
        float acc = 0.f;
        #pragma unroll 4
        for (int kk = 0; kk < 256; kk++) {
            const int k = kc * 256 + kk;
            acc = fmaf(xbar[b * 2048 + k], loadf(skip2, (size_t)k * 2048 + hf, f32), acc);
        }
        atomicAdd(&gS[b * 2048 + hf], acc);
    }
}

// -------------------------------------------------------------------------
// classify (unchanged)
__global__ __launch_bounds__(256) void classify2_k(const float* __restrict__ gA,
                                                   const float* __restrict__ gS,
                                                   const void* __restrict__ b2,
                                                   const void* __restrict__ Wc,
                                                   const void* __restrict__ bc,
                                                   void* __restrict__ out,
                                                   const int* __restrict__ flag)
{
    __shared__ float gv[256];
    const int f32 = *flag;
    const int b = blockIdx.x, f = threadIdx.x;
    float s = 0.f;
    #pragma unroll
    for (int h = 0; h < 8; h++)
        s += gA[(b * 8 + h) * 256 + f] + gS[b * 2048 + h * 256 + f];
    gv[f] = s * (1.0f / 8192.0f) + loadf(b2, f, f32);
    __syncthreads();
    if (f < 10) {
        float acc = loadf(bc, f, f32);
        for (int k = 0; k < 256; k++)
            acc = fmaf(gv[k], loadf(Wc, k * 10 + f, f32), acc);
        if (f32) ((float*)out)[b * 10 + f] = acc;
        else     ((bf16*)out)[b * 10 + f] = f2b(acc);
    }
}

// -------------------------------------------------------------------------
extern "C" void kernel_launch(void* const* d_in, const int* in_sizes, int n_in,
                              void* d_out, int out_size, void* d_ws, size_t ws_size,
                              hipStream_t stream)
{
    (void)in_sizes; (void)n_in; (void)out_size; (void)ws_size;
    const void* feat   = d_in[0];
    const void* mask   = d_in[2];
    const void* W1     = d_in[3];
    const void* a_src1 = d_in[4];
    const void* a_tgt1 = d_in[5];
    const void* skip1  = d_in[6];
    const void* b1     = d_in[7];
    const void* W2     = d_in[8];
    const void* a_src2 = d_in[9];
    const void* a_tgt2 = d_in[10];
    const void* skip2  = d_in[11];
    const void* b2v    = d_in[12];
    const void* Wc     = d_in[13];
    const void* bc     = d_in[14];

    char* ws = (char*)d_ws;
    size_t off = 0;
    auto alloc = [&](size_t bytes) -> void* {
        void* p = ws + off;
        off += (bytes + 255) & ~(size_t)255;
        return p;
    };
    int*   flag  = (int*)alloc(256);
    bf16*  featc = (bf16*)alloc(4096ull * 256 * 2);
    bf16*  W1t   = (bf16*)alloc(2048ull * 256 * 2);
    bf16*  S1t   = (bf16*)alloc(2048ull * 256 * 2);
    bf16*  sk1   = (bf16*)alloc(4096ull * 2048 * 2);
    bf16*  x2    = (bf16*)alloc(4096ull * 2048 * 2);
    bf16*  pT    = (bf16*)alloc(4096ull * 2048 * 2);
    float* ss    = (float*)alloc(32ull * 1024 * 4);
    float* st    = (float*)alloc(32ull * 1024 * 4);
    bf16*  Wa1b  = (bf16*)alloc(16ull * 256 * 2);
    bf16*  Wa2b  = (bf16*)alloc(16ull * 2048 * 2);
    // cbuf, gA, gS, xbar, y contiguous: zeroed in prep_k
    float* cbuf = (float*)alloc(32ull * 1024 * 4);     // 32768 floats
    float* gA   = (float*)alloc(32ull * 256 * 4);      // 8192
    float* gS   = (float*)alloc(4ull * 2048 * 4);      // 8192
    float* xbar = (float*)alloc(4ull * 2048 * 4);      // 8192
    float* y    = (float*)alloc(32ull * 2048 * 4);     // 65536
    const int nzero = 32768 + 3 * 8192 + 65536;        // 122880

    // 1. fused prep (detect + cvt + zero + transposes + wproj1/2)
    prep_k<<<5744, 256, 0, stream>>>(feat, featc, cbuf, nzero, W1, W1t,
                                     skip1, S1t, W2, a_src1, a_tgt1,
                                     a_src2, a_tgt2, Wa1b, Wa2b, flag);
    // 2. dual GEMM: pT (direct transposed layout) + sk1
    gemm_dual<<<dim3(32, 16, 2), 256, 0, stream>>>(featc, W1t, S1t, pT, sk1);
    // 3. layer-1 scores from feat @ Wa1
    score_k<256><<<1024, 256, 0, stream>>>(featc, Wa1b, ss, st);
    // 4. fused layer-1 attention
    attn_fused<<<dim3(32, 32), 256, 0, stream>>>(ss, st, mask, pT, sk1, b1, x2, flag);
    // 5. layer-2 scores from x2 @ Wa2
    score_k<2048><<<1024, 256, 0, stream>>>(x2, Wa2b, ss, st);
    // 6. fused softmax denominators + column sums
    colsoft_k<<<dim3(32, 16), 256, 0, stream>>>(ss, st, mask, cbuf, flag);
    // 7. weighted + plain row aggregation of x2
    yx_k<<<dim3(4, 8, 8), 256, 0, stream>>>(x2, cbuf, y, xbar);
    // 8. fused gamat + skipvec
    gs_k<<<512, 256, 0, stream>>>(W2, skip2, y, xbar, gA, gS, flag);
    // 9. classify
    classify2_k<<<4, 256, 0, stream>>>(gA, gS, b2v, Wc, bc, d_out, flag);
}

// Round 12
// 349.971 us; speedup vs baseline: 1.4409x; 1.1430x over previous
//
#include <hip/hip_runtime.h>
#include <hip/hip_bf16.h>
#include <stdint.h>
#include <stddef.h>

typedef __hip_bfloat16 bf16;
typedef __attribute__((ext_vector_type(8))) short bhalf8;
typedef __attribute__((ext_vector_type(4))) short short4v;
typedef __attribute__((ext_vector_type(4))) float floatx4;

static __device__ __forceinline__ float b2f(bf16 v) { return __bfloat162float(v); }
static __device__ __forceinline__ bf16  f2b(float v) { return __float2bfloat16(v); }
static __device__ __forceinline__ short f2s(float v) {
    union { bf16 b; short s; } u; u.b = __float2bfloat16(v); return u.s;
}
static __device__ __forceinline__ float s2f(short v) {
    union { short s; bf16 b; } u; u.s = v; return b2f(u.b);
}

// dtype-agnostic scalar load: flag==1 -> fp32 data, flag==0 -> bf16 data
static __device__ __forceinline__ float loadf(const void* p, size_t i, int f32) {
    return f32 ? ((const float*)p)[i] : b2f(((const bf16*)p)[i]);
}

// async global->LDS, 16B per lane. LDS dest must be wave-uniform base + lane*16.
static __device__ __forceinline__ void gl_lds16(const void* g, void* l) {
    __builtin_amdgcn_global_load_lds(
        (const __attribute__((address_space(1))) void*)g,
        (__attribute__((address_space(3))) void*)l, 16, 0, 0);
}

// load 4 consecutive bf16 mask values (8B) at 4-aligned element index
static __device__ __forceinline__ void load_mask4b(const bf16* m, size_t idx,
                                                   float* mv) {
    short4v v = *(const short4v*)(m + idx);
    #pragma unroll
    for (int t = 0; t < 4; t++) mv[t] = s2f(v[t]);
}

// -------------------------------------------------------------------------
// Fused prep: inline dtype-detect + [cvt feat | cvt mask->bf16 | zero accum |
// transpose W1 | transpose skip1 | wproj2 | wproj1].
// Segments: [0,4096) cvt feat, +4096 cvt mask, +480 zero, +512 T(W1),
// +512 T(skip1), +512 wproj2, +64 wproj1.  Total 10272 blocks.
__global__ __launch_bounds__(256) void prep_k(const void* __restrict__ feat,
                                              bf16* __restrict__ featc,
                                              const void* __restrict__ mask,
                                              bf16* __restrict__ maskb,
                                              float* __restrict__ zbase, int nzero,
                                              const void* __restrict__ W1,
                                              bf16* __restrict__ W1t,
                                              const void* __restrict__ skip1,
                                              bf16* __restrict__ S1t,
                                              const void* __restrict__ W2,
                                              const void* __restrict__ a_src1,
                                              const void* __restrict__ a_tgt1,
                                              const void* __restrict__ a_src2,
                                              const void* __restrict__ a_tgt2,
                                              bf16* __restrict__ Wa1b,
                                              bf16* __restrict__ Wa2b,
                                              int* __restrict__ flagp)
{
    __shared__ int sflag;
    __shared__ bf16 tile[32][33];
    const int tid = threadIdx.x;

    // inline dtype detection from W1 raw bits (values ~ N(0,0.05))
    if (tid < 64) {
        const unsigned short* s = (const unsigned short*)W1;
        int bad = 0;
        #pragma unroll
        for (int i = 0; i < 4; i++) {
            int e = (s[tid * 4 + i] >> 7) & 0xFF;
            if (e > 0x85 || (e != 0 && e < 0x60)) bad++;
        }
        bad += __shfl_xor(bad, 1, 64);
        bad += __shfl_xor(bad, 2, 64);
        bad += __shfl_xor(bad, 4, 64);
        bad += __shfl_xor(bad, 8, 64);
        bad += __shfl_xor(bad, 16, 64);
        bad += __shfl_xor(bad, 32, 64);
        if (tid == 0) sflag = (bad > 16) ? 1 : 0;
    }
    __syncthreads();
    const int f32 = sflag;

    int id = blockIdx.x;
    if (id == 0 && tid == 0) *flagp = f32;     // publish for later dispatches

    if (id < 4096) {                           // ---- cvt feat -> bf16 ----
        const int i = id * 256 + tid;
        featc[i] = f32 ? f2b(((const float*)feat)[i]) : ((const bf16*)feat)[i];
        return;
    }
    id -= 4096;
    if (id < 4096) {                           // ---- cvt mask -> bf16 (exact for 0/-inf) ----
        const size_t i = (size_t)id * 1024 + tid * 4;
        if (f32) {
            float4 v = *(const float4*)((const float*)mask + i);
            short4v o;
            o[0] = f2s(v.x); o[1] = f2s(v.y); o[2] = f2s(v.z); o[3] = f2s(v.w);
            *(short4v*)(maskb + i) = o;
        } else {
            *(short4v*)(maskb + i) = *(const short4v*)((const bf16*)mask + i);
        }
        return;
    }
    id -= 4096;
    if (id < 480) {                            // ---- zero accumulators ----
        const int i = id * 256 + tid;
        if (i < nzero) zbase[i] = 0.f;
        return;
    }
    id -= 480;
    if (id < 1024) {                           // ---- transposes (256x2048) ----
        const void* in = (id < 512) ? W1 : skip1;
        bf16* out = (id < 512) ? W1t : S1t;
        const int t = id & 511;
        const int bx = t & 63, byy = t >> 6;
        const int tx = tid & 31, ty = tid >> 5;
        const int c0 = bx * 32, r0 = byy * 32;
        #pragma unroll
        for (int yy = ty; yy < 32; yy += 8)
            tile[yy][tx] = f2b(loadf(in, (size_t)(r0 + yy) * 2048 + c0 + tx, f32));
        __syncthreads();
        #pragma unroll
        for (int yy = ty; yy < 32; yy += 8)
            out[(size_t)(c0 + yy) * 256 + r0 + tx] = tile[tx][yy];
        return;
    }
    id -= 1024;
    if (id < 512) {
        // ---- wproj2: Wa2b[hh*2048+k] = sum_f W2[k,h*256+f]*a2[h][f] ----
        // 64 outputs/block, 16/wave.
        const int wave = tid >> 6, lane = tid & 63;
        const int base = id * 64;
        const int hh = base >> 11, h = hh & 7;
        const void* a = (hh < 8) ? a_src2 : a_tgt2;
        float av[4];
        #pragma unroll
        for (int i = 0; i < 4; i++) av[i] = loadf(a, h * 256 + lane * 4 + i, f32);
        #pragma unroll 4
        for (int o = 0; o < 16; o++) {
            const int idx = base + wave * 16 + o;
            const int k = idx & 2047;
            float acc = 0.f;
            #pragma unroll
            for (int i = 0; i < 4; i++)
                acc = fmaf(loadf(W2, (size_t)k * 2048 + h * 256 + lane * 4 + i, f32),
                           av[i], acc);
            #pragma unroll
            for (int off2 = 32; off2; off2 >>= 1) acc += __shfl_down(acc, off2, 64);
            if (lane == 0) Wa2b[idx] = f2b(acc);
        }
        return;
    }
    id -= 512;
    // ---- wproj1: Wa1b[hh*256+k] = sum_f W1[k,h*256+f]*a1[h][f], k<256 ----
    {
        const int wave = tid >> 6, lane = tid & 63;
        const int base = id * 64;                     // id 0..63
        const int hh = base >> 8, h = hh & 7;
        const void* a = (hh < 8) ? a_src1 : a_tgt1;
        float av[4];
        #pragma unroll
        for (int i = 0; i < 4; i++) av[i] = loadf(a, h * 256 + lane * 4 + i, f32);
        #pragma unroll 4
        for (int o = 0; o < 16; o++) {
            const int idx = base + wave * 16 + o;
            const int k = idx & 255;
            float acc = 0.f;
            #pragma unroll
            for (int i = 0; i < 4; i++)
                acc = fmaf(loadf(W1, (size_t)k * 2048 + h * 256 + lane * 4 + i, f32),
                           av[i], acc);
            #pragma unroll
            for (int off2 = 32; off2; off2 >>= 1) acc += __shfl_down(acc, off2, 64);
            if (lane == 0) Wa1b[idx] = f2b(acc);
        }
    }
}

// -------------------------------------------------------------------------
// Dual GEMM, K=256, m97 structure, grid (32,16,2) (unchanged R11):
//  z=0: pT  = W1t(2048x256) @ featc^T  -> per-(b,h) [f][n] layout
//  z=1: sk1 = featc(4096x256) @ S1t^T  -> row-major (node, 2048)
__global__ __launch_bounds__(256) void gemm_dual(const bf16* __restrict__ featc,
                                                 const bf16* __restrict__ W1t,
                                                 const bf16* __restrict__ S1t,
                                                 bf16* __restrict__ pT,
                                                 bf16* __restrict__ sk1)
{
    __shared__ __align__(16) short sA[128][32];
    __shared__ __align__(16) short sB[128][32];
    const int tid = threadIdx.x;
    const int z = blockIdx.z;
    const bf16* A  = z ? featc : W1t;
    const bf16* Bt = z ? S1t   : featc;
    const int mbase = (z ? blockIdx.x : blockIdx.y) * 128;
    const int nbase = (z ? blockIdx.y : blockIdx.x) * 128;
    const int wave = tid >> 6, lane = tid & 63;
    const int wm = wave >> 1, wn = wave & 1;
    const int lrow = lane & 15, quad = lane >> 4;

    floatx4 acc[4][4];
    #pragma unroll
    for (int i = 0; i < 4; i++)
        #pragma unroll
        for (int j = 0; j < 4; j++)
            acc[i][j] = (floatx4){0.f, 0.f, 0.f, 0.f};

    const int srow = wave * 32 + (lane >> 2);
    const int scol = (lane & 3) * 8;
    const bf16* gA0 = A  + (size_t)(mbase + srow) * 256 + scol;
    const bf16* gA1 = gA0 + (size_t)16 * 256;
    const bf16* gB0 = Bt + (size_t)(nbase + srow) * 256 + scol;
    const bf16* gB1 = gB0 + (size_t)16 * 256;
    char* lA0 = (char*)&sA[0][0] + wave * 2048 + lane * 16;
    char* lA1 = lA0 + 1024;
    char* lB0 = (char*)&sB[0][0] + wave * 2048 + lane * 16;
    char* lB1 = lB0 + 1024;

    for (int k0 = 0; k0 < 256; k0 += 32) {
        __syncthreads();
        gl_lds16(gA0 + k0, lA0);
        gl_lds16(gA1 + k0, lA1);
        gl_lds16(gB0 + k0, lB0);
        gl_lds16(gB1 + k0, lB1);
        __syncthreads();
        bhalf8 af[4], bfr[4];
        #pragma unroll
        for (int t = 0; t < 4; t++) af[t]  = *(const bhalf8*)&sA[wm * 64 + t * 16 + lrow][quad * 8];
        #pragma unroll
        for (int t = 0; t < 4; t++) bfr[t] = *(const bhalf8*)&sB[wn * 64 + t * 16 + lrow][quad * 8];
        #pragma unroll
        for (int tm = 0; tm < 4; tm++)
            #pragma unroll
            for (int tn = 0; tn < 4; tn++)
                acc[tm][tn] = __builtin_amdgcn_mfma_f32_16x16x32_bf16(af[tm], bfr[tn], acc[tm][tn], 0, 0, 0);
    }

    #pragma unroll
    for (int tm = 0; tm < 4; tm++) {
        #pragma unroll
        for (int tn = 0; tn < 4; tn++) {
            const int col = nbase + wn * 64 + tn * 16 + lrow;
            #pragma unroll
            for (int r = 0; r < 4; r++) {
                const int row = mbase + wm * 64 + tm * 16 + quad * 4 + r;
                if (z) {
                    sk1[(size_t)row * 2048 + col] = f2b(acc[tm][tn][r]);
                } else {
                    const size_t idx = ((size_t)((col >> 10) * 8 + (row >> 8)) << 18)
                                     + (size_t)(row & 255) * 1024 + (col & 1023);
                    pT[idx] = f2b(acc[tm][tn][r]);
                }
            }
        }
    }
}

// -------------------------------------------------------------------------
// Scores: ss/st[bh][n] = sum_k X[n,k] * Wab[hh][k] (unchanged R11).
template <int K>
__global__ __launch_bounds__(256) void score_k(const bf16* __restrict__ X,
                                               const bf16* __restrict__ Wab,
                                               float* __restrict__ ss,
                                               float* __restrict__ st)
{
    constexpr int VPL = K / 64;
    const int wave = threadIdx.x >> 6, lane = threadIdx.x & 63;
    const int n = blockIdx.x * 4 + wave;
    const int b = n >> 10, nn = n & 1023;

    const bf16* xr = X + (size_t)n * K + lane * VPL;
    float xv[VPL];
    if (VPL == 4) {
        short4v v = *(const short4v*)xr;
        #pragma unroll
        for (int t = 0; t < 4; t++) xv[t] = s2f(v[t]);
    } else {
        #pragma unroll
        for (int c = 0; c < VPL / 8; c++) {
            bhalf8 v = *(const bhalf8*)(xr + c * 8);
            #pragma unroll
            for (int t = 0; t < 8; t++) xv[c * 8 + t] = s2f(v[t]);
        }
    }

    #pragma unroll
    for (int hh = 0; hh < 16; hh++) {
        const bf16* wr = Wab + (size_t)hh * K + lane * VPL;
        float acc = 0.f;
        if (VPL == 4) {
            short4v v = *(const short4v*)wr;
            #pragma unroll
            for (int t = 0; t < 4; t++) acc = fmaf(xv[t], s2f(v[t]), acc);
        } else {
            #pragma unroll
            for (int c = 0; c < VPL / 8; c++) {
                bhalf8 v = *(const bhalf8*)(wr + c * 8);
                #pragma unroll
                for (int t = 0; t < 8; t++) acc = fmaf(xv[c * 8 + t], s2f(v[t]), acc);
            }
        }
        #pragma unroll
        for (int off = 32; off; off >>= 1) acc += __shfl_down(acc, off, 64);
        if (lane == 0) {
            const int h = hh & 7;
            if (hh < 8) ss[(b * 8 + h) * 1024 + nn] = acc;
            else        st[(b * 8 + h) * 1024 + nn] = acc;
        }
    }
}

// -------------------------------------------------------------------------
// Fused layer-1 attention v3 (R9 structure; mask now bf16).
__global__ __launch_bounds__(256) void attn_fused(const float* __restrict__ s_src_t,
                                                  const float* __restrict__ s_tgt_t,
                                                  const bf16* __restrict__ maskb,
                                                  const bf16* __restrict__ pT,
                                                  const bf16* __restrict__ sk,
                                                  const void* __restrict__ bias,
                                                  bf16* __restrict__ x2,
                                                  const int* __restrict__ flag)
{
    __shared__ __align__(16) short sA[2][32][32];    // exp numerators
    __shared__ __align__(16) short sB[2][256][32];   // pT tile (f x k)
    __shared__ short sStgt[1024];                    // s_tgt (bf16)
    __shared__ float sInvl[32];

    const int tid = threadIdx.x;
    const int by = blockIdx.x, bh = blockIdx.y;
    const int b = bh >> 3, h = bh & 7;
    const int f32 = *flag;
    const int wave = tid >> 6, lane = tid & 63;
    const int lrow = lane & 15, quad = lane >> 4;

    #pragma unroll
    for (int q = 0; q < 4; q++)
        sStgt[q * 256 + tid] = f2s(s_tgt_t[bh * 1024 + q * 256 + tid]);

    const int row  = tid >> 3;            // 0..31
    const int col0 = (tid & 7) * 4;       // 0..28
    const float ssr = s_src_t[bh * 1024 + by * 32 + row];
    const size_t mrow0 = ((size_t)(b * 1024 + by * 32 + row)) << 10;

    const bf16* gB = pT + ((size_t)bh << 18) + (size_t)(tid >> 2) * 1024 + (tid & 3) * 8;

    floatx4 acc[2][4];
    #pragma unroll
    for (int i = 0; i < 2; i++)
        #pragma unroll
        for (int j = 0; j < 4; j++)
            acc[i][j] = (floatx4){0.f, 0.f, 0.f, 0.f};

    float lacc = 0.f;

    auto stageB = [&](int k0, int buf) {
        const bf16* g = gB + k0;
        char* l = (char*)&sB[buf][0][0] + tid * 16;
        #pragma unroll
        for (int c = 0; c < 4; c++)
            gl_lds16(g + (size_t)(64 * c) * 1024, l + c * 4096);
    };
    auto genA = [&](int k0, int buf, const float* mv) {
        const short* sp = &sStgt[k0 + col0];
        short4v ev;
        #pragma unroll
        for (int t = 0; t < 4; t++) {
            float x = ssr + s2f(sp[t]);
            x = fmaxf(x, 0.2f * x);          // leaky_relu(0.2)
            float e = __expf(x + mv[t]);
            lacc += e;
            ev[t] = f2s(e);
        }
        *(short4v*)&sA[buf][row][col0] = ev;
    };

    float mv[4];
    stageB(0, 0);
    load_mask4b(maskb, mrow0 + col0, mv);
    __syncthreads();
    genA(0, 0, mv);
    load_mask4b(maskb, mrow0 + 32 + col0, mv);

    int cur = 0;
    for (int k0 = 0; k0 < 1024; k0 += 32, cur ^= 1) {
        __syncthreads();
        if (k0 + 32 < 1024) {
            const int nxt = cur ^ 1;
            stageB(k0 + 32, nxt);
            genA(k0 + 32, nxt, mv);
            if (k0 + 64 < 1024)
                load_mask4b(maskb, mrow0 + k0 + 64 + col0, mv);
        }
        bhalf8 af[2], bfr[4];
        #pragma unroll
        for (int mt = 0; mt < 2; mt++)
            af[mt] = *(const bhalf8*)&sA[cur][mt * 16 + lrow][quad * 8];
        #pragma unroll
        for (int nt = 0; nt < 4; nt++)
            bfr[nt] = *(const bhalf8*)&sB[cur][wave * 64 + nt * 16 + lrow][quad * 8];
        #pragma unroll
        for (int mt = 0; mt < 2; mt++)
            #pragma unroll
            for (int nt = 0; nt < 4; nt++)
                acc[mt][nt] = __builtin_amdgcn_mfma_f32_16x16x32_bf16(af[mt], bfr[nt], acc[mt][nt], 0, 0, 0);
    }

    lacc += __shfl_xor(lacc, 1, 64);
    lacc += __shfl_xor(lacc, 2, 64);
    lacc += __shfl_xor(lacc, 4, 64);
    if ((tid & 7) == 0) sInvl[row] = 1.0f / lacc;
    __syncthreads();

    #pragma unroll
    for (int mt = 0; mt < 2; mt++) {
        #pragma unroll
        for (int r = 0; r < 4; r++) {
            const int rl = mt * 16 + quad * 4 + r;
            const int rg = by * 32 + rl;
            const float il = sInvl[rl];
            #pragma unroll
            for (int nt = 0; nt < 4; nt++) {
                const int col = wave * 64 + nt * 16 + lrow;
                const int hf = h * 256 + col;
                const size_t idx = ((size_t)(b * 1024 + rg)) * 2048 + hf;
                float v = acc[mt][nt][r] * il + b2f(sk[idx]) + loadf(bias, hf, f32);
                v = (v > 0.f) ? v : expm1f(v);     // ELU
                x2[idx] = f2b(v);
            }
        }
    }
}

// -------------------------------------------------------------------------
// Fused layer-2 denominators + weighted column sums (bf16 mask).
__global__ __launch_bounds__(256) void colsoft_k(const float* __restrict__ s_src_t,
                                                 const float* __restrict__ s_tgt_t,
                                                 const bf16* __restrict__ maskb,
                                                 float* __restrict__ c)
{
    __shared__ float sS[64];
    __shared__ float sIl[64];
    const int bh = blockIdx.x, iz = blockIdx.y, b = bh >> 3;
    const int tid = threadIdx.x;
    const int i0 = iz * 64;
    if (tid < 64) sS[tid] = s_src_t[bh * 1024 + i0 + tid];
    __syncthreads();

    {
        const int row = tid >> 2, c4 = tid & 3;
        const float ssr = sS[row];
        const size_t mrow = ((size_t)(b * 1024 + i0 + row)) << 10;
        float l = 0.f;
        #pragma unroll 4
        for (int q = 0; q < 64; q++) {
            const int j = c4 * 256 + q * 4;
            float mv[4];
            load_mask4b(maskb, mrow + j, mv);
            float4 s4 = *(const float4*)(s_tgt_t + bh * 1024 + j);
            float sv[4] = {s4.x, s4.y, s4.z, s4.w};
            #pragma unroll
            for (int t = 0; t < 4; t++) {
                float x = ssr + sv[t];
                x = fmaxf(x, 0.2f * x);
                l += __expf(x + mv[t]);
            }
        }
        l += __shfl_xor(l, 1, 64);
        l += __shfl_xor(l, 2, 64);
        if ((tid & 3) == 0) sIl[row] = 1.0f / l;
    }
    __syncthreads();

    const int j0 = tid * 4;
    float4 s4 = *(const float4*)(s_tgt_t + bh * 1024 + j0);
    float sv[4] = {s4.x, s4.y, s4.z, s4.w};
    float a[4] = {0.f, 0.f, 0.f, 0.f};
    #pragma unroll 4
    for (int r = 0; r < 64; r++) {
        const float sr = sS[r], il = sIl[r];
        float mv[4];
        load_mask4b(maskb, (((size_t)(b * 1024 + i0 + r)) << 10) + j0, mv);
        #pragma unroll
        for (int t = 0; t < 4; t++) {
            float x = sr + sv[t];
            x = fmaxf(x, 0.2f * x);
            a[t] = fmaf(il, __expf(x + mv[t]), a[t]);
        }
    }
    #pragma unroll
    for (int t = 0; t < 4; t++)
        atomicAdd(&c[bh * 1024 + j0 + t], a[t]);
}

// -------------------------------------------------------------------------
// y[bh][k] += sum_{j in 32-chunk} c[bh,j]*x2[b,j,k]; xbar += rowsum.
// Grid (4,8,32) = 1024 blocks, 32-iter loops.
__global__ __launch_bounds__(256) void yx_k(const bf16* __restrict__ x2,
                                            const float* __restrict__ c,
                                            float* __restrict__ y,
                                            float* __restrict__ xbar)
{
    __shared__ float sC[8][32];
    const int b = blockIdx.x, kt = blockIdx.y, jc = blockIdx.z;
    const int t = threadIdx.x;
    const int k = kt * 256 + t;
    const int j0 = jc * 32;
    {
        const int h = t >> 5, jj = t & 31;     // 256 threads = 8h x 32j
        sC[h][jj] = c[(b * 8 + h) * 1024 + j0 + jj];
    }
    __syncthreads();
    float acc[8] = {0.f, 0.f, 0.f, 0.f, 0.f, 0.f, 0.f, 0.f};
    float ax = 0.f;
    #pragma unroll 4
    for (int jj = 0; jj < 32; jj++) {
        const float xv = b2f(x2[((size_t)(b * 1024 + j0 + jj)) * 2048 + k]);
        ax += xv;
        #pragma unroll
        for (int h = 0; h < 8; h++) acc[h] = fmaf(sC[h][jj], xv, acc[h]);
    }
    #pragma unroll
    for (int h = 0; h < 8; h++)
        atomicAdd(&y[(b * 8 + h) * 2048 + k], acc[h]);
    atomicAdd(&xbar[b * 2048 + k], ax);
}

// -------------------------------------------------------------------------
// Fused gamat (blocks [0,1024)) + skipvec (blocks [1024,2048)), 64-iter loops.
__global__ __launch_bounds__(256) void gs_k(const void* __restrict__ W2,
                                            const void* __restrict__ skip2,
                                            const float* __restrict__ y,
                                            const float* __restrict__ xbar,
                                            float* __restrict__ gA,
                                            float* __restrict__ gS,
                                            const int* __restrict__ flagp)
{
    __shared__ float sY[64];
    const int f32 = *flagp;
    int id = blockIdx.x;
    if (id < 1024) {
        // gamat: bh = id & 31, kc = id >> 5 (32 chunks of 64)
        const int bh = id & 31, kc = id >> 5;
        const int h = bh & 7, f = threadIdx.x;
        const int k0 = kc * 64;
        if (threadIdx.x < 64) sY[threadIdx.x] = y[bh * 2048 + k0 + threadIdx.x];
        __syncthreads();
        float acc = 0.f;
        #pragma unroll 4
        for (int kk = 0; kk < 64; kk++)
            acc = fmaf(sY[kk], loadf(W2, (size_t)(k0 + kk) * 2048 + h * 256 + f, f32), acc);
        atomicAdd(&gA[bh * 256 + f], acc);
    } else {
        // skipvec: idx -> b(4), hft(8), kc(32 chunks of 64)
        const int idx = id - 1024;
        const int b = idx & 3, hft = (idx >> 2) & 7, kc = idx >> 5;
        const int hf = hft * 256 + threadIdx.x;
        const int k0 = kc * 64;
        if (threadIdx.x < 64) sY[threadIdx.x] = xbar[b * 2048 + k0 + threadIdx.x];
        __syncthreads();
        float acc = 0.f;
        #pragma unroll 4
        for (int kk = 0; kk < 64; kk++)
            acc = fmaf(sY[kk], loadf(skip2, (size_t)(k0 + kk) * 2048 + hf, f32), acc);
        atomicAdd(&gS[b * 2048 + hf], acc);
    }
}

// -------------------------------------------------------------------------
// classify (unchanged)
__global__ __launch_bounds__(256) void classify2_k(const float* __restrict__ gA,
                                                   const float* __restrict__ gS,
                                                   const void* __restrict__ b2,
                                                   const void* __restrict__ Wc,
                                                   const void* __restrict__ bc,
                                                   void* __restrict__ out,
                                                   const int* __restrict__ flag)
{
    __shared__ float gv[256];
    const int f32 = *flag;
    const int b = blockIdx.x, f = threadIdx.x;
    float s = 0.f;
    #pragma unroll
    for (int h = 0; h < 8; h++)
        s += gA[(b * 8 + h) * 256 + f] + gS[b * 2048 + h * 256 + f];
    gv[f] = s * (1.0f / 8192.0f) + loadf(b2, f, f32);
    __syncthreads();
    if (f < 10) {
        float acc = loadf(bc, f, f32);
        for (int k = 0; k < 256; k++)
            acc = fmaf(gv[k], loadf(Wc, k * 10 + f, f32), acc);
        if (f32) ((float*)out)[b * 10 + f] = acc;
        else     ((bf16*)out)[b * 10 + f] = f2b(acc);
    }
}

// -------------------------------------------------------------------------
extern "C" void kernel_launch(void* const* d_in, const int* in_sizes, int n_in,
                              void* d_out, int out_size, void* d_ws, size_t ws_size,
                              hipStream_t stream)
{
    (void)in_sizes; (void)n_in; (void)out_size; (void)ws_size;
    const void* feat   = d_in[0];
    const void* mask   = d_in[2];
    const void* W1     = d_in[3];
    const void* a_src1 = d_in[4];
    const void* a_tgt1 = d_in[5];
    const void* skip1  = d_in[6];
    const void* b1     = d_in[7];
    const void* W2     = d_in[8];
    const void* a_src2 = d_in[9];
    const void* a_tgt2 = d_in[10];
    const void* skip2  = d_in[11];
    const void* b2v    = d_in[12];
    const void* Wc     = d_in[13];
    const void* bc     = d_in[14];

    char* ws = (char*)d_ws;
    size_t off = 0;
    auto alloc = [&](size_t bytes) -> void* {
        void* p = ws + off;
        off += (bytes + 255) & ~(size_t)255;
        return p;
    };
    int*   flag  = (int*)alloc(256);
    bf16*  featc = (bf16*)alloc(4096ull * 256 * 2);
    bf16*  maskb = (bf16*)alloc(4ull * 1024 * 1024 * 2);
    bf16*  W1t   = (bf16*)alloc(2048ull * 256 * 2);
    bf16*  S1t   = (bf16*)alloc(2048ull * 256 * 2);
    bf16*  sk1   = (bf16*)alloc(4096ull * 2048 * 2);
    bf16*  x2    = (bf16*)alloc(4096ull * 2048 * 2);
    bf16*  pT    = (bf16*)alloc(4096ull * 2048 * 2);
    float* ss    = (float*)alloc(32ull * 1024 * 4);
    float* st    = (float*)alloc(32ull * 1024 * 4);
    bf16*  Wa1b  = (bf16*)alloc(16ull * 256 * 2);
    bf16*  Wa2b  = (bf16*)alloc(16ull * 2048 * 2);
    // cbuf, gA, gS, xbar, y contiguous: zeroed in prep_k
    float* cbuf = (float*)alloc(32ull * 1024 * 4);     // 32768 floats
    float* gA   = (float*)alloc(32ull * 256 * 4);      // 8192
    float* gS   = (float*)alloc(4ull * 2048 * 4);      // 8192
    float* xbar = (float*)alloc(4ull * 2048 * 4);      // 8192
    float* y    = (float*)alloc(32ull * 2048 * 4);     // 65536
    const int nzero = 32768 + 3 * 8192 + 65536;        // 122880

    // 1. fused prep (detect + cvt feat + cvt mask + zero + transposes + wproj)
    prep_k<<<10272, 256, 0, stream>>>(feat, featc, mask, maskb, cbuf, nzero,
                                      W1, W1t, skip1, S1t, W2,
                                      a_src1, a_tgt1, a_src2, a_tgt2,
                                      Wa1b, Wa2b, flag);
    // 2. dual GEMM: pT (direct transposed layout) + sk1
    gemm_dual<<<dim3(32, 16, 2), 256, 0, stream>>>(featc, W1t, S1t, pT, sk1);
    // 3. layer-1 scores from feat @ Wa1
    score_k<256><<<1024, 256, 0, stream>>>(featc, Wa1b, ss, st);
    // 4. fused layer-1 attention
    attn_fused<<<dim3(32, 32), 256, 0, stream>>>(ss, st, maskb, pT, sk1, b1, x2, flag);
    // 5. layer-2 scores from x2 @ Wa2
    score_k<2048><<<1024, 256, 0, stream>>>(x2, Wa2b, ss, st);
    // 6. fused softmax denominators + column sums
    colsoft_k<<<dim3(32, 16), 256, 0, stream>>>(ss, st, maskb, cbuf);
    // 7. weighted + plain row aggregation of x2
    yx_k<<<dim3(4, 8, 32), 256, 0, stream>>>(x2, cbuf, y, xbar);
    // 8. fused gamat + skipvec
    gs_k<<<2048, 256, 0, stream>>>(W2, skip2, y, xbar, gA, gS, flag);
    // 9. classify
    classify2_k<<<4, 256, 0, stream>>>(gA, gS, b2v, Wc, bc, d_out, flag);
}